// Round 13
// baseline (163.604 us; speedup 1.0000x reference)
//
#include <hip/hip_runtime.h>
#include <math.h>

#define BH 48
#define Ss 4096
#define Dd 64
#define Mm 64
#define NCH 16
#define SCALE 0.125f
#define PLN 4096

typedef unsigned int u32;
typedef unsigned short u16;
typedef __attribute__((ext_vector_type(8))) short short8;
typedef __attribute__((ext_vector_type(4))) float floatx4;

union FRAG { uint4 u; short8 s; };

#define MFMA(a,b,c) __builtin_amdgcn_mfma_f32_16x16x32_bf16(a,b,c,0,0,0)

// async global->LDS, 16B per lane; lds base must be wave-uniform
#define GLOAD_LDS(g, l) __builtin_amdgcn_global_load_lds( \
    (const __attribute__((address_space(1))) u32*)(g), \
    (__attribute__((address_space(3))) u32*)(l), 16, 0, 0)

// barrier that waits only LDS ops -> in-flight global loads cross it
__device__ __forceinline__ void lgkm_barrier() {
    asm volatile("s_waitcnt lgkmcnt(0)" ::: "memory");
    __builtin_amdgcn_sched_barrier(0);
    __builtin_amdgcn_s_barrier();
}

__device__ __forceinline__ u32 pack2_hi(float a, float b) {
    return (__float_as_uint(a) >> 16) | (__float_as_uint(b) & 0xFFFF0000u);
}
__device__ __forceinline__ float trunc_bf(float a) {
    return __uint_as_float(__float_as_uint(a) & 0xFFFF0000u);
}
__device__ __forceinline__ void split1(float v, u16& h, u16& l) {
    u32 u = __float_as_uint(v);
    h = (u16)(u >> 16);
    float r = v - __uint_as_float(u & 0xFFFF0000u);
    l = (u16)(__float_as_uint(r) >> 16);
}
__device__ __forceinline__ void split8(const float* v, short8& h, short8& l) {
    FRAG H, L;
    float r[8];
#pragma unroll
    for (int i = 0; i < 8; i++) r[i] = v[i] - trunc_bf(v[i]);
    H.u.x = pack2_hi(v[0], v[1]); H.u.y = pack2_hi(v[2], v[3]);
    H.u.z = pack2_hi(v[4], v[5]); H.u.w = pack2_hi(v[6], v[7]);
    L.u.x = pack2_hi(r[0], r[1]); L.u.y = pack2_hi(r[2], r[3]);
    L.u.z = pack2_hi(r[4], r[5]); L.u.w = pack2_hi(r[6], r[7]);
    h = H.s; l = L.s;
}
// XOR swizzle for [rows][64] bf16 LDS planes.
__device__ __forceinline__ int swz(int row, int col) {
    return row * 64 + ((((col >> 3) ^ (row & 7)) << 3) | (col & 7));
}

// ---------------- K1: landmarks v2 — 2-half split reduction ----------------
__global__ __launch_bounds__(256) void k_landmarks(const float* __restrict__ Q,
                                                   const float* __restrict__ Kg,
                                                   float* __restrict__ qlm,
                                                   float* __restrict__ klm,
                                                   u16* __restrict__ qlmh, u16* __restrict__ qlml,
                                                   u16* __restrict__ klmh, u16* __restrict__ klml) {
    int g = blockIdx.x, bh = blockIdx.y;
    int t = threadIdx.x;
    int m8 = t >> 5, r5 = t & 31, half = r5 >> 4, d4 = r5 & 15;
    int m = g * 8 + m8;
    __shared__ float4 part[8][16];
    const float* src = blockIdx.z ? Kg : Q;
    float* dst = blockIdx.z ? klm : qlm;
    u16* dh = blockIdx.z ? klmh : qlmh;
    u16* dl = blockIdx.z ? klml : qlml;
    const float* base = src + ((size_t)bh * Ss + (size_t)m * 64 + half * 32) * Dd + d4 * 4;
    float4 acc = make_float4(0.f, 0.f, 0.f, 0.f);
#pragma unroll
    for (int l = 0; l < 32; l++) {
        float4 v = *(const float4*)(base + (size_t)l * Dd);
        acc.x += v.x; acc.y += v.y; acc.z += v.z; acc.w += v.w;
    }
    if (half) part[m8][d4] = acc;
    __syncthreads();
    if (!half) {
        float4 o = part[m8][d4];
        acc.x = (acc.x + o.x) * (1.f / 64.f);
        acc.y = (acc.y + o.y) * (1.f / 64.f);
        acc.z = (acc.z + o.z) * (1.f / 64.f);
        acc.w = (acc.w + o.w) * (1.f / 64.f);
        int idx = (bh * Mm + m) * Dd + d4 * 4;
        *(float4*)(dst + idx) = acc;
        float vv[4] = {acc.x, acc.y, acc.z, acc.w};
        u16 hh[4], ll[4];
#pragma unroll
        for (int i = 0; i < 4; i++) split1(vv[i], hh[i], ll[i]);
        *(uint2*)(dh + idx) = make_uint2((u32)hh[0] | ((u32)hh[1] << 16), (u32)hh[2] | ((u32)hh[3] << 16));
        *(uint2*)(dl + idx) = make_uint2((u32)ll[0] | ((u32)ll[1] << 16), (u32)ll[2] | ((u32)ll[3] << 16));
    }
}

// ---------------- K2: landmark softmax matrix + init_coef (block-reduced atomics) ----------------
__global__ __launch_bounds__(256) void k_lmsm(const float* __restrict__ qlm,
                                              const float* __restrict__ klm,
                                              float* __restrict__ smat,
                                              unsigned int* __restrict__ coef) {
    int bh = blockIdx.x, t = threadIdx.x;
    __shared__ float kl[Mm * Dd];
    __shared__ float ql[Mm * Dd];
    __shared__ float Lp[Mm][Mm + 1];
    const float4* kb = (const float4*)(klm + bh * Mm * Dd);
    const float4* qb = (const float4*)(qlm + bh * Mm * Dd);
    for (int i = t; i < Mm * Dd / 4; i += 256) {
        ((float4*)kl)[i] = kb[i];
        ((float4*)ql)[i] = qb[i];
    }
    __syncthreads();
    int n = t >> 2, c = t & 3;
    float p[16];
#pragma unroll
    for (int jj = 0; jj < 16; jj++) {
        int m = c * 16 + jj;
        float s = 0.f;
#pragma unroll
        for (int d4 = 0; d4 < 16; d4++) {
            int d = (((d4 + c * 4) & 15)) * 4;
            float4 kv = *(const float4*)(kl + m * Dd + d);
            float4 qv = *(const float4*)(ql + n * Dd + d);
            s += qv.x * kv.x + qv.y * kv.y + qv.z * kv.z + qv.w * kv.w;
        }
        p[jj] = s * SCALE;
    }
    float mx = -INFINITY;
#pragma unroll
    for (int jj = 0; jj < 16; jj++) mx = fmaxf(mx, p[jj]);
    mx = fmaxf(mx, __shfl_xor(mx, 1));
    mx = fmaxf(mx, __shfl_xor(mx, 2));
    float den = 0.f;
#pragma unroll
    for (int jj = 0; jj < 16; jj++) { p[jj] = __expf(p[jj] - mx); den += p[jj]; }
    den += __shfl_xor(den, 1);
    den += __shfl_xor(den, 2);
    float inv = 1.0f / den;
#pragma unroll
    for (int jj = 0; jj < 16; jj++) Lp[n][c * 16 + jj] = p[jj] * inv;
    __syncthreads();
    float* sg = smat + bh * Mm * Mm;
    for (int i = t; i < Mm * Mm; i += 256) sg[i] = Lp[i >> 6][i & 63];
    if (t < Mm) {
        float cs = 0.f;
#pragma unroll
        for (int nn = 0; nn < Mm; nn++) cs += Lp[nn][t];
#pragma unroll
        for (int off = 1; off < 64; off <<= 1) cs = fmaxf(cs, __shfl_xor(cs, off));
        if (t == 0) atomicMax(coef + 0, __float_as_uint(cs));
    } else if (t < 2 * Mm) {
        int nn = t - Mm; float rs = 0.f;
#pragma unroll
        for (int m = 0; m < Mm; m++) rs += Lp[nn][m];
#pragma unroll
        for (int off = 1; off < 64; off <<= 1) rs = fmaxf(rs, __shfl_xor(rs, off));
        if (t == Mm) atomicMax(coef + 1, __float_as_uint(rs));
    }
}

// ---------------- K3: Newton-Schulz pinv via split-bf16 MFMA ----------------
__device__ __forceinline__ void pinv_pass(const u16* __restrict__ Ah, const u16* __restrict__ Al,
                                          const u16* __restrict__ Bph, const u16* __restrict__ Bpl,
                                          u16* __restrict__ Oh, u16* __restrict__ Ol,
                                          int w, int c, int hi,
                                          float diag, float sgn, float scl) {
    short8 bfh[2], bfl[2];
#pragma unroll
    for (int ks = 0; ks < 2; ks++) {
        bfh[ks] = *(const short8*)&Bph[swz(w * 16 + c, ks * 32 + hi * 8)];
        bfl[ks] = *(const short8*)&Bpl[swz(w * 16 + c, ks * 32 + hi * 8)];
    }
    int j = w * 16 + c;
#pragma unroll
    for (int ta = 0; ta < 4; ta++) {
        floatx4 acc = (floatx4){0.f, 0.f, 0.f, 0.f};
#pragma unroll
        for (int ks = 0; ks < 2; ks++) {
            short8 afh = *(const short8*)&Ah[swz(ta * 16 + c, ks * 32 + hi * 8)];
            short8 afl = *(const short8*)&Al[swz(ta * 16 + c, ks * 32 + hi * 8)];
            acc = MFMA(afh, bfh[ks], acc);
            acc = MFMA(afl, bfh[ks], acc);
            acc = MFMA(afh, bfl[ks], acc);
        }
        u16 oh[4], ol[4];
#pragma unroll
        for (int r = 0; r < 4; r++) {
            int i = ta * 16 + hi * 4 + r;
            float v = scl * (((i == j) ? diag : 0.f) + sgn * acc[r]);
            split1(v, oh[r], ol[r]);
        }
        int o0 = swz(j, ta * 16 + hi * 4);
        *(u32*)&Oh[o0]     = (u32)oh[0] | ((u32)oh[1] << 16);
        *(u32*)&Oh[o0 + 2] = (u32)oh[2] | ((u32)oh[3] << 16);
        *(u32*)&Ol[o0]     = (u32)ol[0] | ((u32)ol[1] << 16);
        *(u32*)&Ol[o0 + 2] = (u32)ol[2] | ((u32)ol[3] << 16);
    }
}

__global__ __launch_bounds__(256) void k_pinv(const float* __restrict__ smat,
                                              const unsigned int* __restrict__ coef,
                                              float* __restrict__ atil) {
    extern __shared__ u16 P[];
    u16* FaH  = P;             u16* FaL  = P + PLN;
    u16* FxcH = P + 2 * PLN;   u16* FxcL = P + 3 * PLN;
    u16* X0H  = P + 4 * PLN;   u16* X0L  = P + 5 * PLN;
    u16* X1H  = P + 6 * PLN;   u16* X1L  = P + 7 * PLN;
    u16* T1H  = P + 8 * PLN;   u16* T1L  = P + 9 * PLN;
    u16* T2H  = P + 10 * PLN;  u16* T2L  = P + 11 * PLN;
    int bh = blockIdx.x, t = threadIdx.x;
    int w = t >> 6, l = t & 63, c = l & 15, hi = l >> 4;
    float inv = 1.0f / (__uint_as_float(coef[0]) * __uint_as_float(coef[1]));
    {
        int r = t >> 2, kq = (t & 3) * 16;
        const float* ar = smat + bh * 4096 + r * 64 + kq;
        float v[16];
#pragma unroll
        for (int q = 0; q < 4; q++) {
            float4 x = *(const float4*)(ar + q * 4);
            v[q * 4 + 0] = x.x; v[q * 4 + 1] = x.y; v[q * 4 + 2] = x.z; v[q * 4 + 3] = x.w;
        }
        short8 h0, l0, h1, l1;
        split8(v, h0, l0); split8(v + 8, h1, l1);
        *(short8*)&FaH[swz(r, kq)] = h0;     *(short8*)&FaH[swz(r, kq + 8)] = h1;
        *(short8*)&FaL[swz(r, kq)] = l0;     *(short8*)&FaL[swz(r, kq + 8)] = l1;
        float vs[16];
#pragma unroll
        for (int q = 0; q < 16; q++) vs[q] = v[q] * inv;
        split8(vs, h0, l0); split8(vs + 8, h1, l1);
        *(short8*)&FxcH[swz(r, kq)] = h0;    *(short8*)&FxcH[swz(r, kq + 8)] = h1;
        *(short8*)&FxcL[swz(r, kq)] = l0;    *(short8*)&FxcL[swz(r, kq + 8)] = l1;
#pragma unroll
        for (int q = 0; q < 16; q++) {
            u16 h, lo; split1(vs[q], h, lo);
            X0H[swz(kq + q, r)] = h;
            X0L[swz(kq + q, r)] = lo;
        }
    }
    __syncthreads();
    u16 *xrH = X0H, *xrL = X0L, *moH = X1H, *moL = X1L;
    for (int it = 0; it < 6; it++) {
        pinv_pass(FxcH, FxcL, FaH, FaL, moH, moL, w, c, hi, 0.f, 1.f, 1.f);
        pinv_pass(FaH, FaL, FxcH, FxcL, T1H, T1L, w, c, hi, 7.f, -1.f, 1.f);
        __syncthreads();
        pinv_pass(moH, moL, T1H, T1L, T2H, T2L, w, c, hi, 15.f, -1.f, 1.f);
        __syncthreads();
        pinv_pass(moH, moL, T2H, T2L, T1H, T1L, w, c, hi, 13.f, -1.f, 1.f);
        __syncthreads();
        pinv_pass(T1H, T1L, xrH, xrL, moH, moL, w, c, hi, 0.f, 1.f, 0.25f);
        pinv_pass(xrH, xrL, T1H, T1L, FxcH, FxcL, w, c, hi, 0.f, 1.f, 0.25f);
        __syncthreads();
        u16* th = xrH; xrH = moH; moH = th;
        u16* tl = xrL; xrL = moL; moL = tl;
    }
    {
        int i = t >> 2, j0 = (t & 3) * 16;
        FRAG h0, l0, h1, l1;
        h0.s = *(const short8*)&xrH[swz(i, j0)];
        l0.s = *(const short8*)&xrL[swz(i, j0)];
        h1.s = *(const short8*)&xrH[swz(i, j0 + 8)];
        l1.s = *(const short8*)&xrL[swz(i, j0 + 8)];
        float* ob = atil + bh * 4096 + i * 64 + j0;
#pragma unroll
        for (int q = 0; q < 8; q++) {
            ob[q]     = __uint_as_float(((u32)(u16)h0.s[q]) << 16) + __uint_as_float(((u32)(u16)l0.s[q]) << 16);
            ob[q + 8] = __uint_as_float(((u32)(u16)h1.s[q]) << 16) + __uint_as_float(((u32)(u16)l1.s[q]) << 16);
        }
    }
}

// ---------------- K4: B_tilde @ V partials via MFMA ----------------
// v5 (on r8 base): V staged via async global_load_lds into unpadded tmp (no
// VGPR roundtrip, no pre-QK vmcnt stall); lgkm-only barriers where only LDS
// state is communicated so in-flight global loads cross them; V(t+1) DMA
// issued right after tile t's tmp reads complete -> a full tile of cover;
// K pipelined in NAMED regs (no arrays, no scratch).
__global__ __launch_bounds__(256) void k_bvp(const float* __restrict__ Kg,
                                             const float* __restrict__ Vg,
                                             const u16* __restrict__ qlmh,
                                             const u16* __restrict__ qlml,
                                             float* __restrict__ pnum,
                                             float* __restrict__ pden) {
    __shared__ __align__(16) u16 Pb[2][4096];     // P split planes [m][s] swizzled
    __shared__ __align__(16) u16 vt[2][4096];     // V^T split planes [d][s] swizzled
    __shared__ __align__(16) float tmp[4096];     // V staging f32 [64][64] (DMA dest)
    int ch = blockIdx.x, bh = blockIdx.y;
    int t = threadIdx.x, w = t >> 6, l = t & 63, c = l & 15, hi = l >> 4;
    const float* Kbh = Kg + (size_t)bh * Ss * Dd;
    const float* Vbh = Vg + (size_t)bh * Ss * Dd;
    const u16* qh = qlmh + bh * Mm * Dd;
    const u16* ql = qlml + bh * Mm * Dd;
    floatx4 pvC[4];
    float denacc[16];
#pragma unroll
    for (int i = 0; i < 4; i++) pvC[i] = (floatx4){0.f, 0.f, 0.f, 0.f};
#pragma unroll
    for (int i = 0; i < 16; i++) denacc[i] = 0.f;
    const float* kp0 = Kbh + (size_t)(ch * 256 + w * 16 + c) * Dd + hi * 8;
    // V DMA: wave w covers rows [w*16, w*16+16); 4 instrs x 16B/lane
    const float* vsrc0 = Vbh + (size_t)(ch * 256 + w * 16) * Dd
                       + ((l >> 4) * Dd + (l & 15) * 4);
    // prologue: stage V(0), load K(0)
#pragma unroll
    for (int i = 0; i < 4; i++)
        GLOAD_LDS(vsrc0 + i * 4 * Dd, &tmp[(w * 16 + i * 4) * 64]);
    float4 kc0 = *(const float4*)(kp0 + 0);
    float4 kc1 = *(const float4*)(kp0 + 4);
    float4 kc2 = *(const float4*)(kp0 + 32);
    float4 kc3 = *(const float4*)(kp0 + 36);
    float4 kn0, kn1, kn2, kn3;
#pragma unroll
    for (int tile = 0; tile < 4; ++tile) {
        // split K(tile)
        short8 kbh[2], kbl[2];
        {
            float kq[8];
            kq[0] = kc0.x; kq[1] = kc0.y; kq[2] = kc0.z; kq[3] = kc0.w;
            kq[4] = kc1.x; kq[5] = kc1.y; kq[6] = kc1.z; kq[7] = kc1.w;
            split8(kq, kbh[0], kbl[0]);
            kq[0] = kc2.x; kq[1] = kc2.y; kq[2] = kc2.z; kq[3] = kc2.w;
            kq[4] = kc3.x; kq[5] = kc3.y; kq[6] = kc3.z; kq[7] = kc3.w;
            split8(kq, kbh[1], kbl[1]);
        }
        // QK^T
        floatx4 qkC[4];
#pragma unroll
        for (int i = 0; i < 4; i++) qkC[i] = (floatx4){0.f, 0.f, 0.f, 0.f};
        __builtin_amdgcn_s_setprio(1);
#pragma unroll
        for (int mt = 0; mt < 4; mt++) {
#pragma unroll
            for (int ks = 0; ks < 2; ks++) {
                short8 aH = *(const short8*)&qh[(mt * 16 + c) * 64 + ks * 32 + hi * 8];
                short8 aL = *(const short8*)&ql[(mt * 16 + c) * 64 + ks * 32 + hi * 8];
                qkC[mt] = MFMA(aH, kbh[ks], qkC[mt]);
                qkC[mt] = MFMA(aL, kbh[ks], qkC[mt]);
                qkC[mt] = MFMA(aH, kbl[ks], qkC[mt]);
            }
        }
        __builtin_amdgcn_s_setprio(0);
#pragma unroll
        for (int mt = 0; mt < 4; mt++) {
#pragma unroll
            for (int r = 0; r < 4; r++) {
                float pv = __expf(qkC[mt][r] * SCALE);
                denacc[mt * 4 + r] += pv;
                int m = mt * 16 + hi * 4 + r;
                u16 h, lo; split1(pv, h, lo);
                Pb[0][swz(m, w * 16 + c)] = h;
                Pb[1][swz(m, w * 16 + c)] = lo;
            }
        }
        __syncthreads();   // A: full barrier — drains V(tile) DMA; Pb visible
        // transpose tmp -> regs (stride-64 f32: 4-way bank alias on 16 reads)
        float v[16];
        {
            int d = t >> 2, sg = t & 3;
#pragma unroll
            for (int j = 0; j < 16; j++) v[j] = tmp[(sg * 16 + j) * 64 + d];
        }
        lgkm_barrier();    // B: tmp reads done (LDS-only) — globals stay in flight
        if (tile < 3) {    // issue V(tile+1) DMA + K(tile+1) loads; drain at next A / use at next top
            const float* vs = vsrc0 + (size_t)(tile + 1) * 64 * Dd;
#pragma unroll
            for (int i = 0; i < 4; i++)
                GLOAD_LDS(vs + i * 4 * Dd, &tmp[(w * 16 + i * 4) * 64]);
            const float* kp = kp0 + (size_t)(tile + 1) * 64 * Dd;
            kn0 = *(const float4*)(kp + 0);
            kn1 = *(const float4*)(kp + 4);
            kn2 = *(const float4*)(kp + 32);
            kn3 = *(const float4*)(kp + 36);
        }
        // split v -> vt planes
        {
            int d = t >> 2, sg = t & 3;
            short8 h0, l0, h1, l1;
            split8(v, h0, l0); split8(v + 8, h1, l1);
            *(short8*)&vt[0][swz(d, sg * 16)] = h0;
            *(short8*)&vt[0][swz(d, sg * 16 + 8)] = h1;
            *(short8*)&vt[1][swz(d, sg * 16)] = l0;
            *(short8*)&vt[1][swz(d, sg * 16 + 8)] = l1;
        }
        lgkm_barrier();    // C: vt ready (LDS-only)
        // PV
        __builtin_amdgcn_s_setprio(1);
#pragma unroll
        for (int ks = 0; ks < 2; ks++) {
            short8 pah = *(const short8*)&Pb[0][swz(w * 16 + c, ks * 32 + hi * 8)];
            short8 pal = *(const short8*)&Pb[1][swz(w * 16 + c, ks * 32 + hi * 8)];
#pragma unroll
            for (int dt = 0; dt < 4; dt++) {
                short8 vh = *(const short8*)&vt[0][swz(dt * 16 + c, ks * 32 + hi * 8)];
                short8 vl = *(const short8*)&vt[1][swz(dt * 16 + c, ks * 32 + hi * 8)];
                pvC[dt] = MFMA(pah, vh, pvC[dt]);
                pvC[dt] = MFMA(pal, vh, pvC[dt]);
                pvC[dt] = MFMA(pah, vl, pvC[dt]);
            }
        }
        __builtin_amdgcn_s_setprio(0);
        lgkm_barrier();    // D: PV's Pb/vt reads done (LDS-only)
        kc0 = kn0; kc1 = kn1; kc2 = kn2; kc3 = kn3;
    }
    float* nb = pnum + (size_t)(bh * NCH + ch) * 4096;
#pragma unroll
    for (int dt = 0; dt < 4; dt++)
#pragma unroll
        for (int r = 0; r < 4; r++)
            nb[(w * 16 + hi * 4 + r) * 64 + dt * 16 + c] = pvC[dt][r];
#pragma unroll
    for (int i = 0; i < 16; i++) {
        float v = denacc[i];
        v += __shfl_xor(v, 1); v += __shfl_xor(v, 2);
        v += __shfl_xor(v, 4); v += __shfl_xor(v, 8);
        denacc[i] = v;
    }
    if (c == 0) {
        float* db = pden + (size_t)((bh * NCH + ch) * 4 + w) * 64;
#pragma unroll
        for (int mt = 0; mt < 4; mt++)
#pragma unroll
            for (int r = 0; r < 4; r++)
                db[mt * 16 + hi * 4 + r] = denacc[mt * 4 + r];
    }
}

// ---------------- K5: combine partials -> bv, abv = A_tilde @ bv, emit abv^T split bf16 ----------------
__global__ __launch_bounds__(256) void k_bvc(const float* __restrict__ pnum,
                                             const float* __restrict__ pden,
                                             const float* __restrict__ atil,
                                             u16* __restrict__ abvh,
                                             u16* __restrict__ abvl) {
    int bh = blockIdx.x, t = threadIdx.x;
    __shared__ float bvs[Mm][Dd + 1];
    __shared__ float Ams[Mm * (Mm + 1)];
    const float* ab = atil + bh * Mm * Mm;
    for (int i = t; i < Mm * Mm; i += 256) Ams[(i >> 6) * 65 + (i & 63)] = ab[i];
    int m = t >> 2, c = t & 3, d0 = c * 16;
    float den = 0.f;
    const float* db = pden + (size_t)bh * NCH * 4 * 64;
#pragma unroll
    for (int i = 0; i < NCH * 4; i++) den += db[i * 64 + m];
    float acc[16];
#pragma unroll
    for (int i = 0; i < 16; i++) acc[i] = 0.f;
    const float* nb = pnum + (size_t)bh * NCH * 4096;
    for (int ch = 0; ch < NCH; ch++) {
        const float4* pa = (const float4*)(nb + ch * 4096 + m * 64 + d0);
#pragma unroll
        for (int q = 0; q < 4; q++) {
            float4 v = pa[q];
            acc[q * 4 + 0] += v.x; acc[q * 4 + 1] += v.y;
            acc[q * 4 + 2] += v.z; acc[q * 4 + 3] += v.w;
        }
    }
    float inv = 1.0f / den;
#pragma unroll
    for (int ii = 0; ii < 16; ii++) bvs[m][d0 + ii] = acc[ii] * inv;
    __syncthreads();
    int j = t & 63, i0 = (t >> 6) << 4;
    float outv[16];
#pragma unroll
    for (int ii = 0; ii < 16; ii++) outv[ii] = 0.f;
#pragma unroll
    for (int k = 0; k < Mm; k++) {
        float bk = bvs[k][j];
#pragma unroll
        for (int ii = 0; ii < 16; ii++) outv[ii] += Ams[(i0 + ii) * 65 + k] * bk;
    }
    u16* oh = abvh + bh * 4096;
    u16* ol = abvl + bh * 4096;
#pragma unroll
    for (int ii = 0; ii < 16; ii++) {
        u16 h, lo; split1(outv[ii], h, lo);
        oh[j * 64 + i0 + ii] = h;
        ol[j * 64 + i0 + ii] = lo;
    }
}

// ---------------- K6: F_tilde softmax fused with F_tilde @ abv via MFMA ----------------
__global__ __launch_bounds__(256) void k_fout(const float* __restrict__ Qg,
                                              const u16* __restrict__ klmh,
                                              const u16* __restrict__ klml,
                                              const u16* __restrict__ abvh,
                                              const u16* __restrict__ abvl,
                                              float* __restrict__ Og) {
    __shared__ __align__(16) u16 skh[4096], skl[4096], sah[4096], sal[4096];
    __shared__ __align__(16) u16 Pw[4][2][1024];
    int sb = blockIdx.x, bh = blockIdx.y;
    int t = threadIdx.x, w = t >> 6, l = t & 63, c = l & 15, hi = l >> 4;
    {
        const uint4* s1 = (const uint4*)(klmh + bh * 4096);
        const uint4* s2 = (const uint4*)(klml + bh * 4096);
        const uint4* s3 = (const uint4*)(abvh + bh * 4096);
        const uint4* s4 = (const uint4*)(abvl + bh * 4096);
#pragma unroll
        for (int i0 = 0; i0 < 512; i0 += 256) {
            int i = i0 + t;
            int row = i >> 3, chk = i & 7;
            int d = row * 8 + (chk ^ (row & 7));
            ((uint4*)skh)[d] = s1[i];
            ((uint4*)skl)[d] = s2[i];
            ((uint4*)sah)[d] = s3[i];
            ((uint4*)sal)[d] = s4[i];
        }
    }
    const float* qbase = Qg + ((size_t)bh * Ss + (size_t)sb * 256 + w * 16 + c) * Dd + hi * 8;
    float4 qv0[4];
    qv0[0] = *(const float4*)(qbase + 0);
    qv0[1] = *(const float4*)(qbase + 4);
    qv0[2] = *(const float4*)(qbase + 32);
    qv0[3] = *(const float4*)(qbase + 36);
    __syncthreads();
#pragma unroll
    for (int ti = 0; ti < 4; ti++) {
        float4 qn[4];
        if (ti < 3) {
            const float* q2 = qbase + (ti + 1) * 64 * Dd;
            qn[0] = *(const float4*)(q2 + 0);
            qn[1] = *(const float4*)(q2 + 4);
            qn[2] = *(const float4*)(q2 + 32);
            qn[3] = *(const float4*)(q2 + 36);
        }
        short8 qah[2], qal[2];
        {
            float qq[8];
            qq[0] = qv0[0].x; qq[1] = qv0[0].y; qq[2] = qv0[0].z; qq[3] = qv0[0].w;
            qq[4] = qv0[1].x; qq[5] = qv0[1].y; qq[6] = qv0[1].z; qq[7] = qv0[1].w;
            split8(qq, qah[0], qal[0]);
            qq[0] = qv0[2].x; qq[1] = qv0[2].y; qq[2] = qv0[2].z; qq[3] = qv0[2].w;
            qq[4] = qv0[3].x; qq[5] = qv0[3].y; qq[6] = qv0[3].z; qq[7] = qv0[3].w;
            split8(qq, qah[1], qal[1]);
        }
        floatx4 qkC[4];
#pragma unroll
        for (int i = 0; i < 4; i++) qkC[i] = (floatx4){0.f, 0.f, 0.f, 0.f};
        __builtin_amdgcn_s_setprio(1);
#pragma unroll
        for (int mt = 0; mt < 4; mt++) {
#pragma unroll
            for (int ks = 0; ks < 2; ks++) {
                short8 bH = *(const short8*)&skh[swz(mt * 16 + c, ks * 32 + hi * 8)];
                short8 bL = *(const short8*)&skl[swz(mt * 16 + c, ks * 32 + hi * 8)];
                qkC[mt] = MFMA(qah[ks], bH, qkC[mt]);
                qkC[mt] = MFMA(qal[ks], bH, qkC[mt]);
                qkC[mt] = MFMA(qah[ks], bL, qkC[mt]);
            }
        }
        __builtin_amdgcn_s_setprio(0);
        float p[16], dsum[4];
#pragma unroll
        for (int r = 0; r < 4; r++) dsum[r] = 0.f;
#pragma unroll
        for (int mt = 0; mt < 4; mt++)
#pragma unroll
            for (int r = 0; r < 4; r++) {
                float pv = __expf(qkC[mt][r] * SCALE);
                p[mt * 4 + r] = pv;
                dsum[r] += pv;
            }
#pragma unroll
        for (int r = 0; r < 4; r++) {
            float v = dsum[r];
            v += __shfl_xor(v, 1); v += __shfl_xor(v, 2);
            v += __shfl_xor(v, 4); v += __shfl_xor(v, 8);
            dsum[r] = 1.0f / v;
        }
#pragma unroll
        for (int mt = 0; mt < 4; mt++)
#pragma unroll
            for (int r = 0; r < 4; r++) {
                float pv = p[mt * 4 + r] * dsum[r];
                u16 h, lo; split1(pv, h, lo);
                Pw[w][0][swz(hi * 4 + r, mt * 16 + c)] = h;
                Pw[w][1][swz(hi * 4 + r, mt * 16 + c)] = lo;
            }
        asm volatile("s_waitcnt lgkmcnt(0)" ::: "memory");
        __builtin_amdgcn_sched_barrier(0);
        short8 pah[2], pal[2];
#pragma unroll
        for (int ks = 0; ks < 2; ks++) {
            pah[ks] = *(const short8*)&Pw[w][0][swz(c, ks * 32 + hi * 8)];
            pal[ks] = *(const short8*)&Pw[w][1][swz(c, ks * 32 + hi * 8)];
        }
        floatx4 oC[4];
#pragma unroll
        for (int i = 0; i < 4; i++) oC[i] = (floatx4){0.f, 0.f, 0.f, 0.f};
        __builtin_amdgcn_s_setprio(1);
#pragma unroll
        for (int dt = 0; dt < 4; dt++) {
#pragma unroll
            for (int ks = 0; ks < 2; ks++) {
                short8 bH = *(const short8*)&sah[swz(dt * 16 + c, ks * 32 + hi * 8)];
                short8 bL = *(const short8*)&sal[swz(dt * 16 + c, ks * 32 + hi * 8)];
                oC[dt] = MFMA(pah[ks], bH, oC[dt]);
                oC[dt] = MFMA(pal[ks], bH, oC[dt]);
                oC[dt] = MFMA(pah[ks], bL, oC[dt]);
            }
        }
        __builtin_amdgcn_s_setprio(0);
        float* ob = Og + ((size_t)bh * Ss + (size_t)sb * 256 + ti * 64 + w * 16) * Dd;
#pragma unroll
        for (int dt = 0; dt < 4; dt++)
#pragma unroll
            for (int r = 0; r < 4; r++)
                ob[(hi * 4 + r) * 64 + dt * 16 + c] = oC[dt][r];
        qv0[0] = qn[0]; qv0[1] = qn[1]; qv0[2] = qn[2]; qv0[3] = qn[3];
    }
}

extern "C" void kernel_launch(void* const* d_in, const int* in_sizes, int n_in,
                              void* d_out, int out_size, void* d_ws, size_t ws_size,
                              hipStream_t stream) {
    const float* Q = (const float*)d_in[0];
    const float* K = (const float*)d_in[1];
    const float* V = (const float*)d_in[2];
    float* out = (float*)d_out;
    float* ws = (float*)d_ws;
    unsigned int* coef = (unsigned int*)d_ws;
    float* qlm  = ws + 16;
    float* klm  = qlm  + BH * Mm * Dd;
    float* smat = klm  + BH * Mm * Dd;
    float* atil = smat + BH * Mm * Mm;
    float* pnum = atil + BH * Mm * Mm;
    float* pden = pnum + (size_t)BH * NCH * Mm * Dd;
    u16* ub   = (u16*)(pden + (size_t)BH * NCH * 4 * 64);
    u16* qlmh = ub;
    u16* qlml = qlmh + BH * Mm * Dd;
    u16* klmh = qlml + BH * Mm * Dd;
    u16* klml = klmh + BH * Mm * Dd;
    u16* abvh = klml + BH * Mm * Dd;
    u16* abvl = abvh + BH * Mm * Dd;

    hipMemsetAsync(d_ws, 0, 64, stream);

    k_landmarks<<<dim3(8, BH, 2), dim3(256), 0, stream>>>(Q, K, qlm, klm, qlmh, qlml, klmh, klml);
    k_lmsm<<<dim3(BH), dim3(256), 0, stream>>>(qlm, klm, smat, coef);
    k_pinv<<<dim3(BH), dim3(256), 12 * PLN * 2, stream>>>(smat, coef, atil);
    k_bvp<<<dim3(NCH, BH), dim3(256), 0, stream>>>(K, V, qlmh, qlml, pnum, pden);
    k_bvc<<<dim3(BH), dim3(256), 0, stream>>>(pnum, pden, atil, abvh, abvl);
    k_fout<<<dim3(Ss / 256, BH), dim3(256), 0, stream>>>(Q, klmh, klml, abvh, abvl, out);
}

// Round 14
// 161.021 us; speedup vs baseline: 1.0160x; 1.0160x over previous
//
#include <hip/hip_runtime.h>
#include <math.h>

#define BH 48
#define Ss 4096
#define Dd 64
#define Mm 64
#define NCH 16
#define SCALE 0.125f
#define PLN 4096

typedef unsigned int u32;
typedef unsigned short u16;
typedef __attribute__((ext_vector_type(8))) short short8;
typedef __attribute__((ext_vector_type(4))) float floatx4;

union FRAG { uint4 u; short8 s; };

#define MFMA(a,b,c) __builtin_amdgcn_mfma_f32_16x16x32_bf16(a,b,c,0,0,0)

// async global->LDS, 16B per lane; lds base must be wave-uniform
#define GLOAD_LDS(g, l) __builtin_amdgcn_global_load_lds( \
    (const __attribute__((address_space(1))) u32*)(g), \
    (__attribute__((address_space(3))) u32*)(l), 16, 0, 0)

// barrier that waits only LDS ops -> in-flight global loads cross it
__device__ __forceinline__ void lgkm_barrier() {
    asm volatile("s_waitcnt lgkmcnt(0)" ::: "memory");
    __builtin_amdgcn_sched_barrier(0);
    __builtin_amdgcn_s_barrier();
}

__device__ __forceinline__ u32 pack2_hi(float a, float b) {
    return (__float_as_uint(a) >> 16) | (__float_as_uint(b) & 0xFFFF0000u);
}
__device__ __forceinline__ float trunc_bf(float a) {
    return __uint_as_float(__float_as_uint(a) & 0xFFFF0000u);
}
__device__ __forceinline__ void split1(float v, u16& h, u16& l) {
    u32 u = __float_as_uint(v);
    h = (u16)(u >> 16);
    float r = v - __uint_as_float(u & 0xFFFF0000u);
    l = (u16)(__float_as_uint(r) >> 16);
}
__device__ __forceinline__ void split8(const float* v, short8& h, short8& l) {
    FRAG H, L;
    float r[8];
#pragma unroll
    for (int i = 0; i < 8; i++) r[i] = v[i] - trunc_bf(v[i]);
    H.u.x = pack2_hi(v[0], v[1]); H.u.y = pack2_hi(v[2], v[3]);
    H.u.z = pack2_hi(v[4], v[5]); H.u.w = pack2_hi(v[6], v[7]);
    L.u.x = pack2_hi(r[0], r[1]); L.u.y = pack2_hi(r[2], r[3]);
    L.u.z = pack2_hi(r[4], r[5]); L.u.w = pack2_hi(r[6], r[7]);
    h = H.s; l = L.s;
}
// XOR swizzle for [rows][64] bf16 LDS planes.
__device__ __forceinline__ int swz(int row, int col) {
    return row * 64 + ((((col >> 3) ^ (row & 7)) << 3) | (col & 7));
}

// ---------------- K1: landmarks v2 — 2-half split reduction ----------------
__global__ __launch_bounds__(256) void k_landmarks(const float* __restrict__ Q,
                                                   const float* __restrict__ Kg,
                                                   float* __restrict__ qlm,
                                                   float* __restrict__ klm,
                                                   u16* __restrict__ qlmh, u16* __restrict__ qlml,
                                                   u16* __restrict__ klmh, u16* __restrict__ klml) {
    int g = blockIdx.x, bh = blockIdx.y;
    int t = threadIdx.x;
    int m8 = t >> 5, r5 = t & 31, half = r5 >> 4, d4 = r5 & 15;
    int m = g * 8 + m8;
    __shared__ float4 part[8][16];
    const float* src = blockIdx.z ? Kg : Q;
    float* dst = blockIdx.z ? klm : qlm;
    u16* dh = blockIdx.z ? klmh : qlmh;
    u16* dl = blockIdx.z ? klml : qlml;
    const float* base = src + ((size_t)bh * Ss + (size_t)m * 64 + half * 32) * Dd + d4 * 4;
    float4 acc = make_float4(0.f, 0.f, 0.f, 0.f);
#pragma unroll
    for (int l = 0; l < 32; l++) {
        float4 v = *(const float4*)(base + (size_t)l * Dd);
        acc.x += v.x; acc.y += v.y; acc.z += v.z; acc.w += v.w;
    }
    if (half) part[m8][d4] = acc;
    __syncthreads();
    if (!half) {
        float4 o = part[m8][d4];
        acc.x = (acc.x + o.x) * (1.f / 64.f);
        acc.y = (acc.y + o.y) * (1.f / 64.f);
        acc.z = (acc.z + o.z) * (1.f / 64.f);
        acc.w = (acc.w + o.w) * (1.f / 64.f);
        int idx = (bh * Mm + m) * Dd + d4 * 4;
        *(float4*)(dst + idx) = acc;
        float vv[4] = {acc.x, acc.y, acc.z, acc.w};
        u16 hh[4], ll[4];
#pragma unroll
        for (int i = 0; i < 4; i++) split1(vv[i], hh[i], ll[i]);
        *(uint2*)(dh + idx) = make_uint2((u32)hh[0] | ((u32)hh[1] << 16), (u32)hh[2] | ((u32)hh[3] << 16));
        *(uint2*)(dl + idx) = make_uint2((u32)ll[0] | ((u32)ll[1] << 16), (u32)ll[2] | ((u32)ll[3] << 16));
    }
}

// ---------------- K2: landmark softmax matrix + init_coef (block-reduced atomics) ----------------
__global__ __launch_bounds__(256) void k_lmsm(const float* __restrict__ qlm,
                                              const float* __restrict__ klm,
                                              float* __restrict__ smat,
                                              unsigned int* __restrict__ coef) {
    int bh = blockIdx.x, t = threadIdx.x;
    __shared__ float kl[Mm * Dd];
    __shared__ float ql[Mm * Dd];
    __shared__ float Lp[Mm][Mm + 1];
    const float4* kb = (const float4*)(klm + bh * Mm * Dd);
    const float4* qb = (const float4*)(qlm + bh * Mm * Dd);
    for (int i = t; i < Mm * Dd / 4; i += 256) {
        ((float4*)kl)[i] = kb[i];
        ((float4*)ql)[i] = qb[i];
    }
    __syncthreads();
    int n = t >> 2, c = t & 3;
    float p[16];
#pragma unroll
    for (int jj = 0; jj < 16; jj++) {
        int m = c * 16 + jj;
        float s = 0.f;
#pragma unroll
        for (int d4 = 0; d4 < 16; d4++) {
            int d = (((d4 + c * 4) & 15)) * 4;
            float4 kv = *(const float4*)(kl + m * Dd + d);
            float4 qv = *(const float4*)(ql + n * Dd + d);
            s += qv.x * kv.x + qv.y * kv.y + qv.z * kv.z + qv.w * kv.w;
        }
        p[jj] = s * SCALE;
    }
    float mx = -INFINITY;
#pragma unroll
    for (int jj = 0; jj < 16; jj++) mx = fmaxf(mx, p[jj]);
    mx = fmaxf(mx, __shfl_xor(mx, 1));
    mx = fmaxf(mx, __shfl_xor(mx, 2));
    float den = 0.f;
#pragma unroll
    for (int jj = 0; jj < 16; jj++) { p[jj] = __expf(p[jj] - mx); den += p[jj]; }
    den += __shfl_xor(den, 1);
    den += __shfl_xor(den, 2);
    float inv = 1.0f / den;
#pragma unroll
    for (int jj = 0; jj < 16; jj++) Lp[n][c * 16 + jj] = p[jj] * inv;
    __syncthreads();
    float* sg = smat + bh * Mm * Mm;
    for (int i = t; i < Mm * Mm; i += 256) sg[i] = Lp[i >> 6][i & 63];
    if (t < Mm) {
        float cs = 0.f;
#pragma unroll
        for (int nn = 0; nn < Mm; nn++) cs += Lp[nn][t];
#pragma unroll
        for (int off = 1; off < 64; off <<= 1) cs = fmaxf(cs, __shfl_xor(cs, off));
        if (t == 0) atomicMax(coef + 0, __float_as_uint(cs));
    } else if (t < 2 * Mm) {
        int nn = t - Mm; float rs = 0.f;
#pragma unroll
        for (int m = 0; m < Mm; m++) rs += Lp[nn][m];
#pragma unroll
        for (int off = 1; off < 64; off <<= 1) rs = fmaxf(rs, __shfl_xor(rs, off));
        if (t == Mm) atomicMax(coef + 1, __float_as_uint(rs));
    }
}

// ---------------- K3: Newton-Schulz pinv via split-bf16 MFMA ----------------
__device__ __forceinline__ void pinv_pass(const u16* __restrict__ Ah, const u16* __restrict__ Al,
                                          const u16* __restrict__ Bph, const u16* __restrict__ Bpl,
                                          u16* __restrict__ Oh, u16* __restrict__ Ol,
                                          int w, int c, int hi,
                                          float diag, float sgn, float scl) {
    short8 bfh[2], bfl[2];
#pragma unroll
    for (int ks = 0; ks < 2; ks++) {
        bfh[ks] = *(const short8*)&Bph[swz(w * 16 + c, ks * 32 + hi * 8)];
        bfl[ks] = *(const short8*)&Bpl[swz(w * 16 + c, ks * 32 + hi * 8)];
    }
    int j = w * 16 + c;
#pragma unroll
    for (int ta = 0; ta < 4; ta++) {
        floatx4 acc = (floatx4){0.f, 0.f, 0.f, 0.f};
#pragma unroll
        for (int ks = 0; ks < 2; ks++) {
            short8 afh = *(const short8*)&Ah[swz(ta * 16 + c, ks * 32 + hi * 8)];
            short8 afl = *(const short8*)&Al[swz(ta * 16 + c, ks * 32 + hi * 8)];
            acc = MFMA(afh, bfh[ks], acc);
            acc = MFMA(afl, bfh[ks], acc);
            acc = MFMA(afh, bfl[ks], acc);
        }
        u16 oh[4], ol[4];
#pragma unroll
        for (int r = 0; r < 4; r++) {
            int i = ta * 16 + hi * 4 + r;
            float v = scl * (((i == j) ? diag : 0.f) + sgn * acc[r]);
            split1(v, oh[r], ol[r]);
        }
        int o0 = swz(j, ta * 16 + hi * 4);
        *(u32*)&Oh[o0]     = (u32)oh[0] | ((u32)oh[1] << 16);
        *(u32*)&Oh[o0 + 2] = (u32)oh[2] | ((u32)oh[3] << 16);
        *(u32*)&Ol[o0]     = (u32)ol[0] | ((u32)ol[1] << 16);
        *(u32*)&Ol[o0 + 2] = (u32)ol[2] | ((u32)ol[3] << 16);
    }
}

__global__ __launch_bounds__(256) void k_pinv(const float* __restrict__ smat,
                                              const unsigned int* __restrict__ coef,
                                              float* __restrict__ atil) {
    extern __shared__ u16 P[];
    u16* FaH  = P;             u16* FaL  = P + PLN;
    u16* FxcH = P + 2 * PLN;   u16* FxcL = P + 3 * PLN;
    u16* X0H  = P + 4 * PLN;   u16* X0L  = P + 5 * PLN;
    u16* X1H  = P + 6 * PLN;   u16* X1L  = P + 7 * PLN;
    u16* T1H  = P + 8 * PLN;   u16* T1L  = P + 9 * PLN;
    u16* T2H  = P + 10 * PLN;  u16* T2L  = P + 11 * PLN;
    int bh = blockIdx.x, t = threadIdx.x;
    int w = t >> 6, l = t & 63, c = l & 15, hi = l >> 4;
    float inv = 1.0f / (__uint_as_float(coef[0]) * __uint_as_float(coef[1]));
    {
        int r = t >> 2, kq = (t & 3) * 16;
        const float* ar = smat + bh * 4096 + r * 64 + kq;
        float v[16];
#pragma unroll
        for (int q = 0; q < 4; q++) {
            float4 x = *(const float4*)(ar + q * 4);
            v[q * 4 + 0] = x.x; v[q * 4 + 1] = x.y; v[q * 4 + 2] = x.z; v[q * 4 + 3] = x.w;
        }
        short8 h0, l0, h1, l1;
        split8(v, h0, l0); split8(v + 8, h1, l1);
        *(short8*)&FaH[swz(r, kq)] = h0;     *(short8*)&FaH[swz(r, kq + 8)] = h1;
        *(short8*)&FaL[swz(r, kq)] = l0;     *(short8*)&FaL[swz(r, kq + 8)] = l1;
        float vs[16];
#pragma unroll
        for (int q = 0; q < 16; q++) vs[q] = v[q] * inv;
        split8(vs, h0, l0); split8(vs + 8, h1, l1);
        *(short8*)&FxcH[swz(r, kq)] = h0;    *(short8*)&FxcH[swz(r, kq + 8)] = h1;
        *(short8*)&FxcL[swz(r, kq)] = l0;    *(short8*)&FxcL[swz(r, kq + 8)] = l1;
#pragma unroll
        for (int q = 0; q < 16; q++) {
            u16 h, lo; split1(vs[q], h, lo);
            X0H[swz(kq + q, r)] = h;
            X0L[swz(kq + q, r)] = lo;
        }
    }
    __syncthreads();
    u16 *xrH = X0H, *xrL = X0L, *moH = X1H, *moL = X1L;
    for (int it = 0; it < 6; it++) {
        pinv_pass(FxcH, FxcL, FaH, FaL, moH, moL, w, c, hi, 0.f, 1.f, 1.f);
        pinv_pass(FaH, FaL, FxcH, FxcL, T1H, T1L, w, c, hi, 7.f, -1.f, 1.f);
        __syncthreads();
        pinv_pass(moH, moL, T1H, T1L, T2H, T2L, w, c, hi, 15.f, -1.f, 1.f);
        __syncthreads();
        pinv_pass(moH, moL, T2H, T2L, T1H, T1L, w, c, hi, 13.f, -1.f, 1.f);
        __syncthreads();
        pinv_pass(T1H, T1L, xrH, xrL, moH, moL, w, c, hi, 0.f, 1.f, 0.25f);
        pinv_pass(xrH, xrL, T1H, T1L, FxcH, FxcL, w, c, hi, 0.f, 1.f, 0.25f);
        __syncthreads();
        u16* th = xrH; xrH = moH; moH = th;
        u16* tl = xrL; xrL = moL; moL = tl;
    }
    {
        int i = t >> 2, j0 = (t & 3) * 16;
        FRAG h0, l0, h1, l1;
        h0.s = *(const short8*)&xrH[swz(i, j0)];
        l0.s = *(const short8*)&xrL[swz(i, j0)];
        h1.s = *(const short8*)&xrH[swz(i, j0 + 8)];
        l1.s = *(const short8*)&xrL[swz(i, j0 + 8)];
        float* ob = atil + bh * 4096 + i * 64 + j0;
#pragma unroll
        for (int q = 0; q < 8; q++) {
            ob[q]     = __uint_as_float(((u32)(u16)h0.s[q]) << 16) + __uint_as_float(((u32)(u16)l0.s[q]) << 16);
            ob[q + 8] = __uint_as_float(((u32)(u16)h1.s[q]) << 16) + __uint_as_float(((u32)(u16)l1.s[q]) << 16);
        }
    }
}

// ---------------- K4: B_tilde @ V partials via MFMA ----------------
// v6: async V DMA with FIFO-correct issue order. Per tile, AFTER barrier B
// (all tmp reads retired): issue K(t+1) reg-loads FIRST, then V(t+1) DMA.
// FIFO waitcnt => top-of-loop K-split waits vmcnt(4) leaving the V DMA in
// flight under QK/exp; the only vmcnt(0) drain (barrier A, __syncthreads)
// lands exactly when V is needed. r13's flaw was V-before-K issue order
// (K use forced vmcnt(0), killing the cover).
__global__ __launch_bounds__(256) void k_bvp(const float* __restrict__ Kg,
                                             const float* __restrict__ Vg,
                                             const u16* __restrict__ qlmh,
                                             const u16* __restrict__ qlml,
                                             float* __restrict__ pnum,
                                             float* __restrict__ pden) {
    __shared__ __align__(16) u16 Pb[2][4096];     // P split planes [m][s] swizzled
    __shared__ __align__(16) u16 vt[2][4096];     // V^T split planes [d][s] swizzled
    __shared__ __align__(16) float tmp[4096];     // V staging f32 [64][64] (DMA dest)
    int ch = blockIdx.x, bh = blockIdx.y;
    int t = threadIdx.x, w = t >> 6, l = t & 63, c = l & 15, hi = l >> 4;
    const float* Kbh = Kg + (size_t)bh * Ss * Dd;
    const float* Vbh = Vg + (size_t)bh * Ss * Dd;
    const u16* qh = qlmh + bh * Mm * Dd;
    const u16* ql = qlml + bh * Mm * Dd;
    floatx4 pvC[4];
    float denacc[16];
#pragma unroll
    for (int i = 0; i < 4; i++) pvC[i] = (floatx4){0.f, 0.f, 0.f, 0.f};
#pragma unroll
    for (int i = 0; i < 16; i++) denacc[i] = 0.f;
    const float* kp0 = Kbh + (size_t)(ch * 256 + w * 16 + c) * Dd + hi * 8;
    // V DMA: wave w covers rows [w*16, w*16+16); 4 instrs x 16B/lane
    const float* vsrc0 = Vbh + (size_t)(ch * 256 + w * 16) * Dd
                       + ((l >> 4) * Dd + (l & 15) * 4);
    // prologue: K(0) loads FIRST (oldest in FIFO), then V(0) DMA
    float4 kc0 = *(const float4*)(kp0 + 0);
    float4 kc1 = *(const float4*)(kp0 + 4);
    float4 kc2 = *(const float4*)(kp0 + 32);
    float4 kc3 = *(const float4*)(kp0 + 36);
#pragma unroll
    for (int i = 0; i < 4; i++)
        GLOAD_LDS(vsrc0 + i * 4 * Dd, &tmp[(w * 16 + i * 4) * 64]);
    float4 kn0, kn1, kn2, kn3;
#pragma unroll
    for (int tile = 0; tile < 4; ++tile) {
        // split K(tile) — compiler waits vmcnt(4): K oldest, V DMA stays in flight
        short8 kbh[2], kbl[2];
        {
            float kq[8];
            kq[0] = kc0.x; kq[1] = kc0.y; kq[2] = kc0.z; kq[3] = kc0.w;
            kq[4] = kc1.x; kq[5] = kc1.y; kq[6] = kc1.z; kq[7] = kc1.w;
            split8(kq, kbh[0], kbl[0]);
            kq[0] = kc2.x; kq[1] = kc2.y; kq[2] = kc2.z; kq[3] = kc2.w;
            kq[4] = kc3.x; kq[5] = kc3.y; kq[6] = kc3.z; kq[7] = kc3.w;
            split8(kq, kbh[1], kbl[1]);
        }
        // QK^T (V DMA in flight underneath)
        floatx4 qkC[4];
#pragma unroll
        for (int i = 0; i < 4; i++) qkC[i] = (floatx4){0.f, 0.f, 0.f, 0.f};
        __builtin_amdgcn_s_setprio(1);
#pragma unroll
        for (int mt = 0; mt < 4; mt++) {
#pragma unroll
            for (int ks = 0; ks < 2; ks++) {
                short8 aH = *(const short8*)&qh[(mt * 16 + c) * 64 + ks * 32 + hi * 8];
                short8 aL = *(const short8*)&ql[(mt * 16 + c) * 64 + ks * 32 + hi * 8];
                qkC[mt] = MFMA(aH, kbh[ks], qkC[mt]);
                qkC[mt] = MFMA(aL, kbh[ks], qkC[mt]);
                qkC[mt] = MFMA(aH, kbl[ks], qkC[mt]);
            }
        }
        __builtin_amdgcn_s_setprio(0);
#pragma unroll
        for (int mt = 0; mt < 4; mt++) {
#pragma unroll
            for (int r = 0; r < 4; r++) {
                float pv = __expf(qkC[mt][r] * SCALE);
                denacc[mt * 4 + r] += pv;
                int m = mt * 16 + hi * 4 + r;
                u16 h, lo; split1(pv, h, lo);
                Pb[0][swz(m, w * 16 + c)] = h;
                Pb[1][swz(m, w * 16 + c)] = lo;
            }
        }
        __syncthreads();   // A: drains V(tile) DMA (vmcnt 0); Pb visible
        // transpose tmp -> regs (stride-64 f32; 4-way alias acceptable)
        float v[16];
        {
            int d = t >> 2, sg = t & 3;
#pragma unroll
            for (int j = 0; j < 16; j++) v[j] = tmp[(sg * 16 + j) * 64 + d];
        }
        lgkm_barrier();    // B: all tmp reads retired (LDS-only barrier)
        if (tile < 3) {    // K(t+1) FIRST, V(t+1) DMA SECOND (FIFO order)
            const float* kp = kp0 + (size_t)(tile + 1) * 64 * Dd;
            kn0 = *(const float4*)(kp + 0);
            kn1 = *(const float4*)(kp + 4);
            kn2 = *(const float4*)(kp + 32);
            kn3 = *(const float4*)(kp + 36);
            const float* vs = vsrc0 + (size_t)(tile + 1) * 64 * Dd;
#pragma unroll
            for (int i = 0; i < 4; i++)
                GLOAD_LDS(vs + i * 4 * Dd, &tmp[(w * 16 + i * 4) * 64]);
        }
        // split v -> vt planes
        {
            int d = t >> 2, sg = t & 3;
            short8 h0, l0, h1, l1;
            split8(v, h0, l0); split8(v + 8, h1, l1);
            *(short8*)&vt[0][swz(d, sg * 16)] = h0;
            *(short8*)&vt[0][swz(d, sg * 16 + 8)] = h1;
            *(short8*)&vt[1][swz(d, sg * 16)] = l0;
            *(short8*)&vt[1][swz(d, sg * 16 + 8)] = l1;
        }
        lgkm_barrier();    // C: vt ready (LDS-only; K/V prefetch stays in flight)
        // PV
        __builtin_amdgcn_s_setprio(1);
#pragma unroll
        for (int ks = 0; ks < 2; ks++) {
            short8 pah = *(const short8*)&Pb[0][swz(w * 16 + c, ks * 32 + hi * 8)];
            short8 pal = *(const short8*)&Pb[1][swz(w * 16 + c, ks * 32 + hi * 8)];
#pragma unroll
            for (int dt = 0; dt < 4; dt++) {
                short8 vh = *(const short8*)&vt[0][swz(dt * 16 + c, ks * 32 + hi * 8)];
                short8 vl = *(const short8*)&vt[1][swz(dt * 16 + c, ks * 32 + hi * 8)];
                pvC[dt] = MFMA(pah, vh, pvC[dt]);
                pvC[dt] = MFMA(pal, vh, pvC[dt]);
                pvC[dt] = MFMA(pah, vl, pvC[dt]);
            }
        }
        __builtin_amdgcn_s_setprio(0);
        lgkm_barrier();    // D: PV's Pb/vt reads done (LDS-only)
        kc0 = kn0; kc1 = kn1; kc2 = kn2; kc3 = kn3;
    }
    float* nb = pnum + (size_t)(bh * NCH + ch) * 4096;
#pragma unroll
    for (int dt = 0; dt < 4; dt++)
#pragma unroll
        for (int r = 0; r < 4; r++)
            nb[(w * 16 + hi * 4 + r) * 64 + dt * 16 + c] = pvC[dt][r];
#pragma unroll
    for (int i = 0; i < 16; i++) {
        float v = denacc[i];
        v += __shfl_xor(v, 1); v += __shfl_xor(v, 2);
        v += __shfl_xor(v, 4); v += __shfl_xor(v, 8);
        denacc[i] = v;
    }
    if (c == 0) {
        float* db = pden + (size_t)((bh * NCH + ch) * 4 + w) * 64;
#pragma unroll
        for (int mt = 0; mt < 4; mt++)
#pragma unroll
            for (int r = 0; r < 4; r++)
                db[mt * 16 + hi * 4 + r] = denacc[mt * 4 + r];
    }
}

// ---------------- K5: combine partials -> bv, abv = A_tilde @ bv, emit abv^T split bf16 ----------------
__global__ __launch_bounds__(256) void k_bvc(const float* __restrict__ pnum,
                                             const float* __restrict__ pden,
                                             const float* __restrict__ atil,
                                             u16* __restrict__ abvh,
                                             u16* __restrict__ abvl) {
    int bh = blockIdx.x, t = threadIdx.x;
    __shared__ float bvs[Mm][Dd + 1];
    __shared__ float Ams[Mm * (Mm + 1)];
    const float* ab = atil + bh * Mm * Mm;
    for (int i = t; i < Mm * Mm; i += 256) Ams[(i >> 6) * 65 + (i & 63)] = ab[i];
    int m = t >> 2, c = t & 3, d0 = c * 16;
    float den = 0.f;
    const float* db = pden + (size_t)bh * NCH * 4 * 64;
#pragma unroll
    for (int i = 0; i < NCH * 4; i++) den += db[i * 64 + m];
    float acc[16];
#pragma unroll
    for (int i = 0; i < 16; i++) acc[i] = 0.f;
    const float* nb = pnum + (size_t)bh * NCH * 4096;
    for (int ch = 0; ch < NCH; ch++) {
        const float4* pa = (const float4*)(nb + ch * 4096 + m * 64 + d0);
#pragma unroll
        for (int q = 0; q < 4; q++) {
            float4 v = pa[q];
            acc[q * 4 + 0] += v.x; acc[q * 4 + 1] += v.y;
            acc[q * 4 + 2] += v.z; acc[q * 4 + 3] += v.w;
        }
    }
    float inv = 1.0f / den;
#pragma unroll
    for (int ii = 0; ii < 16; ii++) bvs[m][d0 + ii] = acc[ii] * inv;
    __syncthreads();
    int j = t & 63, i0 = (t >> 6) << 4;
    float outv[16];
#pragma unroll
    for (int ii = 0; ii < 16; ii++) outv[ii] = 0.f;
#pragma unroll
    for (int k = 0; k < Mm; k++) {
        float bk = bvs[k][j];
#pragma unroll
        for (int ii = 0; ii < 16; ii++) outv[ii] += Ams[(i0 + ii) * 65 + k] * bk;
    }
    u16* oh = abvh + bh * 4096;
    u16* ol = abvl + bh * 4096;
#pragma unroll
    for (int ii = 0; ii < 16; ii++) {
        u16 h, lo; split1(outv[ii], h, lo);
        oh[j * 64 + i0 + ii] = h;
        ol[j * 64 + i0 + ii] = lo;
    }
}

// ---------------- K6: F_tilde softmax fused with F_tilde @ abv via MFMA ----------------
__global__ __launch_bounds__(256) void k_fout(const float* __restrict__ Qg,
                                              const u16* __restrict__ klmh,
                                              const u16* __restrict__ klml,
                                              const u16* __restrict__ abvh,
                                              const u16* __restrict__ abvl,
                                              float* __restrict__ Og) {
    __shared__ __align__(16) u16 skh[4096], skl[4096], sah[4096], sal[4096];
    __shared__ __align__(16) u16 Pw[4][2][1024];
    int sb = blockIdx.x, bh = blockIdx.y;
    int t = threadIdx.x, w = t >> 6, l = t & 63, c = l & 15, hi = l >> 4;
    {
        const uint4* s1 = (const uint4*)(klmh + bh * 4096);
        const uint4* s2 = (const uint4*)(klml + bh * 4096);
        const uint4* s3 = (const uint4*)(abvh + bh * 4096);
        const uint4* s4 = (const uint4*)(abvl + bh * 4096);
#pragma unroll
        for (int i0 = 0; i0 < 512; i0 += 256) {
            int i = i0 + t;
            int row = i >> 3, chk = i & 7;
            int d = row * 8 + (chk ^ (row & 7));
            ((uint4*)skh)[d] = s1[i];
            ((uint4*)skl)[d] = s2[i];
            ((uint4*)sah)[d] = s3[i];
            ((uint4*)sal)[d] = s4[i];
        }
    }
    const float* qbase = Qg + ((size_t)bh * Ss + (size_t)sb * 256 + w * 16 + c) * Dd + hi * 8;
    float4 qv0[4];
    qv0[0] = *(const float4*)(qbase + 0);
    qv0[1] = *(const float4*)(qbase + 4);
    qv0[2] = *(const float4*)(qbase + 32);
    qv0[3] = *(const float4*)(qbase + 36);
    __syncthreads();
#pragma unroll
    for (int ti = 0; ti < 4; ti++) {
        float4 qn[4];
        if (ti < 3) {
            const float* q2 = qbase + (ti + 1) * 64 * Dd;
            qn[0] = *(const float4*)(q2 + 0);
            qn[1] = *(const float4*)(q2 + 4);
            qn[2] = *(const float4*)(q2 + 32);
            qn[3] = *(const float4*)(q2 + 36);
        }
        short8 qah[2], qal[2];
        {
            float qq[8];
            qq[0] = qv0[0].x; qq[1] = qv0[0].y; qq[2] = qv0[0].z; qq[3] = qv0[0].w;
            qq[4] = qv0[1].x; qq[5] = qv0[1].y; qq[6] = qv0[1].z; qq[7] = qv0[1].w;
            split8(qq, qah[0], qal[0]);
            qq[0] = qv0[2].x; qq[1] = qv0[2].y; qq[2] = qv0[2].z; qq[3] = qv0[2].w;
            qq[4] = qv0[3].x; qq[5] = qv0[3].y; qq[6] = qv0[3].z; qq[7] = qv0[3].w;
            split8(qq, qah[1], qal[1]);
        }
        floatx4 qkC[4];
#pragma unroll
        for (int i = 0; i < 4; i++) qkC[i] = (floatx4){0.f, 0.f, 0.f, 0.f};
        __builtin_amdgcn_s_setprio(1);
#pragma unroll
        for (int mt = 0; mt < 4; mt++) {
#pragma unroll
            for (int ks = 0; ks < 2; ks++) {
                short8 bH = *(const short8*)&skh[swz(mt * 16 + c, ks * 32 + hi * 8)];
                short8 bL = *(const short8*)&skl[swz(mt * 16 + c, ks * 32 + hi * 8)];
                qkC[mt] = MFMA(qah[ks], bH, qkC[mt]);
                qkC[mt] = MFMA(qal[ks], bH, qkC[mt]);
                qkC[mt] = MFMA(qah[ks], bL, qkC[mt]);
            }
        }
        __builtin_amdgcn_s_setprio(0);
        float p[16], dsum[4];
#pragma unroll
        for (int r = 0; r < 4; r++) dsum[r] = 0.f;
#pragma unroll
        for (int mt = 0; mt < 4; mt++)
#pragma unroll
            for (int r = 0; r < 4; r++) {
                float pv = __expf(qkC[mt][r] * SCALE);
                p[mt * 4 + r] = pv;
                dsum[r] += pv;
            }
#pragma unroll
        for (int r = 0; r < 4; r++) {
            float v = dsum[r];
            v += __shfl_xor(v, 1); v += __shfl_xor(v, 2);
            v += __shfl_xor(v, 4); v += __shfl_xor(v, 8);
            dsum[r] = 1.0f / v;
        }
#pragma unroll
        for (int mt = 0; mt < 4; mt++)
#pragma unroll
            for (int r = 0; r < 4; r++) {
                float pv = p[mt * 4 + r] * dsum[r];
                u16 h, lo; split1(pv, h, lo);
                Pw[w][0][swz(hi * 4 + r, mt * 16 + c)] = h;
                Pw[w][1][swz(hi * 4 + r, mt * 16 + c)] = lo;
            }
        asm volatile("s_waitcnt lgkmcnt(0)" ::: "memory");
        __builtin_amdgcn_sched_barrier(0);
        short8 pah[2], pal[2];
#pragma unroll
        for (int ks = 0; ks < 2; ks++) {
            pah[ks] = *(const short8*)&Pw[w][0][swz(c, ks * 32 + hi * 8)];
            pal[ks] = *(const short8*)&Pw[w][1][swz(c, ks * 32 + hi * 8)];
        }
        floatx4 oC[4];
#pragma unroll
        for (int i = 0; i < 4; i++) oC[i] = (floatx4){0.f, 0.f, 0.f, 0.f};
        __builtin_amdgcn_s_setprio(1);
#pragma unroll
        for (int dt = 0; dt < 4; dt++) {
#pragma unroll
            for (int ks = 0; ks < 2; ks++) {
                short8 bH = *(const short8*)&sah[swz(dt * 16 + c, ks * 32 + hi * 8)];
                short8 bL = *(const short8*)&sal[swz(dt * 16 + c, ks * 32 + hi * 8)];
                oC[dt] = MFMA(pah[ks], bH, oC[dt]);
                oC[dt] = MFMA(pal[ks], bH, oC[dt]);
                oC[dt] = MFMA(pah[ks], bL, oC[dt]);
            }
        }
        __builtin_amdgcn_s_setprio(0);
        float* ob = Og + ((size_t)bh * Ss + (size_t)sb * 256 + ti * 64 + w * 16) * Dd;
#pragma unroll
        for (int dt = 0; dt < 4; dt++)
#pragma unroll
            for (int r = 0; r < 4; r++)
                ob[(hi * 4 + r) * 64 + dt * 16 + c] = oC[dt][r];
        qv0[0] = qn[0]; qv0[1] = qn[1]; qv0[2] = qn[2]; qv0[3] = qn[3];
    }
}

extern "C" void kernel_launch(void* const* d_in, const int* in_sizes, int n_in,
                              void* d_out, int out_size, void* d_ws, size_t ws_size,
                              hipStream_t stream) {
    const float* Q = (const float*)d_in[0];
    const float* K = (const float*)d_in[1];
    const float* V = (const float*)d_in[2];
    float* out = (float*)d_out;
    float* ws = (float*)d_ws;
    unsigned int* coef = (unsigned int*)d_ws;
    float* qlm  = ws + 16;
    float* klm  = qlm  + BH * Mm * Dd;
    float* smat = klm  + BH * Mm * Dd;
    float* atil = smat + BH * Mm * Mm;
    float* pnum = atil + BH * Mm * Mm;
    float* pden = pnum + (size_t)BH * NCH * Mm * Dd;
    u16* ub   = (u16*)(pden + (size_t)BH * NCH * 4 * 64);
    u16* qlmh = ub;
    u16* qlml = qlmh + BH * Mm * Dd;
    u16* klmh = qlml + BH * Mm * Dd;
    u16* klml = klmh + BH * Mm * Dd;
    u16* abvh = klml + BH * Mm * Dd;
    u16* abvl = abvh + BH * Mm * Dd;

    hipMemsetAsync(d_ws, 0, 64, stream);

    k_landmarks<<<dim3(8, BH, 2), dim3(256), 0, stream>>>(Q, K, qlm, klm, qlmh, qlml, klmh, klml);
    k_lmsm<<<dim3(BH), dim3(256), 0, stream>>>(qlm, klm, smat, coef);
    k_pinv<<<dim3(BH), dim3(256), 12 * PLN * 2, stream>>>(smat, coef, atil);
    k_bvp<<<dim3(NCH, BH), dim3(256), 0, stream>>>(K, V, qlmh, qlml, pnum, pden);
    k_bvc<<<dim3(BH), dim3(256), 0, stream>>>(pnum, pden, atil, abvh, abvl);
    k_fout<<<dim3(Ss / 256, BH), dim3(256), 0, stream>>>(Q, klmh, klml, abvh, abvl, out);
}

// Round 15
// 149.602 us; speedup vs baseline: 1.0936x; 1.0763x over previous
//
#include <hip/hip_runtime.h>
#include <math.h>

#define BH 48
#define Ss 4096
#define Dd 64
#define Mm 64
#define NCH 16
#define SCALE 0.125f
#define PLN 4096

typedef unsigned int u32;
typedef unsigned short u16;
typedef __attribute__((ext_vector_type(8))) short short8;
typedef __attribute__((ext_vector_type(4))) float floatx4;

union FRAG { uint4 u; short8 s; };

#define MFMA(a,b,c) __builtin_amdgcn_mfma_f32_16x16x32_bf16(a,b,c,0,0,0)

__device__ __forceinline__ u32 pack2_hi(float a, float b) {
    return (__float_as_uint(a) >> 16) | (__float_as_uint(b) & 0xFFFF0000u);
}
__device__ __forceinline__ float trunc_bf(float a) {
    return __uint_as_float(__float_as_uint(a) & 0xFFFF0000u);
}
__device__ __forceinline__ void split1(float v, u16& h, u16& l) {
    u32 u = __float_as_uint(v);
    h = (u16)(u >> 16);
    float r = v - __uint_as_float(u & 0xFFFF0000u);
    l = (u16)(__float_as_uint(r) >> 16);
}
__device__ __forceinline__ void split8(const float* v, short8& h, short8& l) {
    FRAG H, L;
    float r[8];
#pragma unroll
    for (int i = 0; i < 8; i++) r[i] = v[i] - trunc_bf(v[i]);
    H.u.x = pack2_hi(v[0], v[1]); H.u.y = pack2_hi(v[2], v[3]);
    H.u.z = pack2_hi(v[4], v[5]); H.u.w = pack2_hi(v[6], v[7]);
    L.u.x = pack2_hi(r[0], r[1]); L.u.y = pack2_hi(r[2], r[3]);
    L.u.z = pack2_hi(r[4], r[5]); L.u.w = pack2_hi(r[6], r[7]);
    h = H.s; l = L.s;
}
// XOR swizzle for [rows][64] bf16 LDS planes.
__device__ __forceinline__ int swz(int row, int col) {
    return row * 64 + ((((col >> 3) ^ (row & 7)) << 3) | (col & 7));
}

// ---------------- K1: landmarks v2 — 2-half split reduction ----------------
__global__ __launch_bounds__(256) void k_landmarks(const float* __restrict__ Q,
                                                   const float* __restrict__ Kg,
                                                   float* __restrict__ qlm,
                                                   float* __restrict__ klm,
                                                   u16* __restrict__ qlmh, u16* __restrict__ qlml,
                                                   u16* __restrict__ klmh, u16* __restrict__ klml) {
    int g = blockIdx.x, bh = blockIdx.y;
    int t = threadIdx.x;
    int m8 = t >> 5, r5 = t & 31, half = r5 >> 4, d4 = r5 & 15;
    int m = g * 8 + m8;
    __shared__ float4 part[8][16];
    const float* src = blockIdx.z ? Kg : Q;
    float* dst = blockIdx.z ? klm : qlm;
    u16* dh = blockIdx.z ? klmh : qlmh;
    u16* dl = blockIdx.z ? klml : qlml;
    const float* base = src + ((size_t)bh * Ss + (size_t)m * 64 + half * 32) * Dd + d4 * 4;
    float4 acc = make_float4(0.f, 0.f, 0.f, 0.f);
#pragma unroll
    for (int l = 0; l < 32; l++) {
        float4 v = *(const float4*)(base + (size_t)l * Dd);
        acc.x += v.x; acc.y += v.y; acc.z += v.z; acc.w += v.w;
    }
    if (half) part[m8][d4] = acc;
    __syncthreads();
    if (!half) {
        float4 o = part[m8][d4];
        acc.x = (acc.x + o.x) * (1.f / 64.f);
        acc.y = (acc.y + o.y) * (1.f / 64.f);
        acc.z = (acc.z + o.z) * (1.f / 64.f);
        acc.w = (acc.w + o.w) * (1.f / 64.f);
        int idx = (bh * Mm + m) * Dd + d4 * 4;
        *(float4*)(dst + idx) = acc;
        float vv[4] = {acc.x, acc.y, acc.z, acc.w};
        u16 hh[4], ll[4];
#pragma unroll
        for (int i = 0; i < 4; i++) split1(vv[i], hh[i], ll[i]);
        *(uint2*)(dh + idx) = make_uint2((u32)hh[0] | ((u32)hh[1] << 16), (u32)hh[2] | ((u32)hh[3] << 16));
        *(uint2*)(dl + idx) = make_uint2((u32)ll[0] | ((u32)ll[1] << 16), (u32)ll[2] | ((u32)ll[3] << 16));
    }
}

// ---------------- K2: landmark softmax matrix + init_coef (block-reduced atomics) ----------------
__global__ __launch_bounds__(256) void k_lmsm(const float* __restrict__ qlm,
                                              const float* __restrict__ klm,
                                              float* __restrict__ smat,
                                              unsigned int* __restrict__ coef) {
    int bh = blockIdx.x, t = threadIdx.x;
    __shared__ float kl[Mm * Dd];
    __shared__ float ql[Mm * Dd];
    __shared__ float Lp[Mm][Mm + 1];
    const float4* kb = (const float4*)(klm + bh * Mm * Dd);
    const float4* qb = (const float4*)(qlm + bh * Mm * Dd);
    for (int i = t; i < Mm * Dd / 4; i += 256) {
        ((float4*)kl)[i] = kb[i];
        ((float4*)ql)[i] = qb[i];
    }
    __syncthreads();
    int n = t >> 2, c = t & 3;
    float p[16];
#pragma unroll
    for (int jj = 0; jj < 16; jj++) {
        int m = c * 16 + jj;
        float s = 0.f;
#pragma unroll
        for (int d4 = 0; d4 < 16; d4++) {
            int d = (((d4 + c * 4) & 15)) * 4;
            float4 kv = *(const float4*)(kl + m * Dd + d);
            float4 qv = *(const float4*)(ql + n * Dd + d);
            s += qv.x * kv.x + qv.y * kv.y + qv.z * kv.z + qv.w * kv.w;
        }
        p[jj] = s * SCALE;
    }
    float mx = -INFINITY;
#pragma unroll
    for (int jj = 0; jj < 16; jj++) mx = fmaxf(mx, p[jj]);
    mx = fmaxf(mx, __shfl_xor(mx, 1));
    mx = fmaxf(mx, __shfl_xor(mx, 2));
    float den = 0.f;
#pragma unroll
    for (int jj = 0; jj < 16; jj++) { p[jj] = __expf(p[jj] - mx); den += p[jj]; }
    den += __shfl_xor(den, 1);
    den += __shfl_xor(den, 2);
    float inv = 1.0f / den;
#pragma unroll
    for (int jj = 0; jj < 16; jj++) Lp[n][c * 16 + jj] = p[jj] * inv;
    __syncthreads();
    float* sg = smat + bh * Mm * Mm;
    for (int i = t; i < Mm * Mm; i += 256) sg[i] = Lp[i >> 6][i & 63];
    if (t < Mm) {
        float cs = 0.f;
#pragma unroll
        for (int nn = 0; nn < Mm; nn++) cs += Lp[nn][t];
#pragma unroll
        for (int off = 1; off < 64; off <<= 1) cs = fmaxf(cs, __shfl_xor(cs, off));
        if (t == 0) atomicMax(coef + 0, __float_as_uint(cs));
    } else if (t < 2 * Mm) {
        int nn = t - Mm; float rs = 0.f;
#pragma unroll
        for (int m = 0; m < Mm; m++) rs += Lp[nn][m];
#pragma unroll
        for (int off = 1; off < 64; off <<= 1) rs = fmaxf(rs, __shfl_xor(rs, off));
        if (t == Mm) atomicMax(coef + 1, __float_as_uint(rs));
    }
}

// ---------------- K3: Newton-Schulz pinv via split-bf16 MFMA ----------------
__device__ __forceinline__ void pinv_pass(const u16* __restrict__ Ah, const u16* __restrict__ Al,
                                          const u16* __restrict__ Bph, const u16* __restrict__ Bpl,
                                          u16* __restrict__ Oh, u16* __restrict__ Ol,
                                          int w, int c, int hi,
                                          float diag, float sgn, float scl) {
    short8 bfh[2], bfl[2];
#pragma unroll
    for (int ks = 0; ks < 2; ks++) {
        bfh[ks] = *(const short8*)&Bph[swz(w * 16 + c, ks * 32 + hi * 8)];
        bfl[ks] = *(const short8*)&Bpl[swz(w * 16 + c, ks * 32 + hi * 8)];
    }
    int j = w * 16 + c;
#pragma unroll
    for (int ta = 0; ta < 4; ta++) {
        floatx4 acc = (floatx4){0.f, 0.f, 0.f, 0.f};
#pragma unroll
        for (int ks = 0; ks < 2; ks++) {
            short8 afh = *(const short8*)&Ah[swz(ta * 16 + c, ks * 32 + hi * 8)];
            short8 afl = *(const short8*)&Al[swz(ta * 16 + c, ks * 32 + hi * 8)];
            acc = MFMA(afh, bfh[ks], acc);
            acc = MFMA(afl, bfh[ks], acc);
            acc = MFMA(afh, bfl[ks], acc);
        }
        u16 oh[4], ol[4];
#pragma unroll
        for (int r = 0; r < 4; r++) {
            int i = ta * 16 + hi * 4 + r;
            float v = scl * (((i == j) ? diag : 0.f) + sgn * acc[r]);
            split1(v, oh[r], ol[r]);
        }
        int o0 = swz(j, ta * 16 + hi * 4);
        *(u32*)&Oh[o0]     = (u32)oh[0] | ((u32)oh[1] << 16);
        *(u32*)&Oh[o0 + 2] = (u32)oh[2] | ((u32)oh[3] << 16);
        *(u32*)&Ol[o0]     = (u32)ol[0] | ((u32)ol[1] << 16);
        *(u32*)&Ol[o0 + 2] = (u32)ol[2] | ((u32)ol[3] << 16);
    }
}

__global__ __launch_bounds__(256) void k_pinv(const float* __restrict__ smat,
                                              const unsigned int* __restrict__ coef,
                                              float* __restrict__ atil) {
    extern __shared__ u16 P[];
    u16* FaH  = P;             u16* FaL  = P + PLN;
    u16* FxcH = P + 2 * PLN;   u16* FxcL = P + 3 * PLN;
    u16* X0H  = P + 4 * PLN;   u16* X0L  = P + 5 * PLN;
    u16* X1H  = P + 6 * PLN;   u16* X1L  = P + 7 * PLN;
    u16* T1H  = P + 8 * PLN;   u16* T1L  = P + 9 * PLN;
    u16* T2H  = P + 10 * PLN;  u16* T2L  = P + 11 * PLN;
    int bh = blockIdx.x, t = threadIdx.x;
    int w = t >> 6, l = t & 63, c = l & 15, hi = l >> 4;
    float inv = 1.0f / (__uint_as_float(coef[0]) * __uint_as_float(coef[1]));
    {
        int r = t >> 2, kq = (t & 3) * 16;
        const float* ar = smat + bh * 4096 + r * 64 + kq;
        float v[16];
#pragma unroll
        for (int q = 0; q < 4; q++) {
            float4 x = *(const float4*)(ar + q * 4);
            v[q * 4 + 0] = x.x; v[q * 4 + 1] = x.y; v[q * 4 + 2] = x.z; v[q * 4 + 3] = x.w;
        }
        short8 h0, l0, h1, l1;
        split8(v, h0, l0); split8(v + 8, h1, l1);
        *(short8*)&FaH[swz(r, kq)] = h0;     *(short8*)&FaH[swz(r, kq + 8)] = h1;
        *(short8*)&FaL[swz(r, kq)] = l0;     *(short8*)&FaL[swz(r, kq + 8)] = l1;
        float vs[16];
#pragma unroll
        for (int q = 0; q < 16; q++) vs[q] = v[q] * inv;
        split8(vs, h0, l0); split8(vs + 8, h1, l1);
        *(short8*)&FxcH[swz(r, kq)] = h0;    *(short8*)&FxcH[swz(r, kq + 8)] = h1;
        *(short8*)&FxcL[swz(r, kq)] = l0;    *(short8*)&FxcL[swz(r, kq + 8)] = l1;
#pragma unroll
        for (int q = 0; q < 16; q++) {
            u16 h, lo; split1(vs[q], h, lo);
            X0H[swz(kq + q, r)] = h;
            X0L[swz(kq + q, r)] = lo;
        }
    }
    __syncthreads();
    u16 *xrH = X0H, *xrL = X0L, *moH = X1H, *moL = X1L;
    for (int it = 0; it < 6; it++) {
        pinv_pass(FxcH, FxcL, FaH, FaL, moH, moL, w, c, hi, 0.f, 1.f, 1.f);
        pinv_pass(FaH, FaL, FxcH, FxcL, T1H, T1L, w, c, hi, 7.f, -1.f, 1.f);
        __syncthreads();
        pinv_pass(moH, moL, T1H, T1L, T2H, T2L, w, c, hi, 15.f, -1.f, 1.f);
        __syncthreads();
        pinv_pass(moH, moL, T2H, T2L, T1H, T1L, w, c, hi, 13.f, -1.f, 1.f);
        __syncthreads();
        pinv_pass(T1H, T1L, xrH, xrL, moH, moL, w, c, hi, 0.f, 1.f, 0.25f);
        pinv_pass(xrH, xrL, T1H, T1L, FxcH, FxcL, w, c, hi, 0.f, 1.f, 0.25f);
        __syncthreads();
        u16* th = xrH; xrH = moH; moH = th;
        u16* tl = xrL; xrL = moL; moL = tl;
    }
    {
        int i = t >> 2, j0 = (t & 3) * 16;
        FRAG h0, l0, h1, l1;
        h0.s = *(const short8*)&xrH[swz(i, j0)];
        l0.s = *(const short8*)&xrL[swz(i, j0)];
        h1.s = *(const short8*)&xrH[swz(i, j0 + 8)];
        l1.s = *(const short8*)&xrL[swz(i, j0 + 8)];
        float* ob = atil + bh * 4096 + i * 64 + j0;
#pragma unroll
        for (int q = 0; q < 8; q++) {
            ob[q]     = __uint_as_float(((u32)(u16)h0.s[q]) << 16) + __uint_as_float(((u32)(u16)l0.s[q]) << 16);
            ob[q + 8] = __uint_as_float(((u32)(u16)h1.s[q]) << 16) + __uint_as_float(((u32)(u16)l1.s[q]) << 16);
        }
    }
}

// ---------------- K4: B_tilde @ V partials via MFMA (r8 skeleton; K loads hoisted
// between V loads and V ds_writes so K+V HBM latencies overlap via FIFO vmcnt) ----------------
__global__ __launch_bounds__(256) void k_bvp(const float* __restrict__ Kg,
                                             const float* __restrict__ Vg,
                                             const u16* __restrict__ qlmh,
                                             const u16* __restrict__ qlml,
                                             float* __restrict__ pnum,
                                             float* __restrict__ pden) {
    __shared__ __align__(16) u16 Pb[2][4096];
    __shared__ __align__(16) u16 vt[2][4096];
    __shared__ __align__(16) float tmp[64 * 68];
    int ch = blockIdx.x, bh = blockIdx.y;
    int t = threadIdx.x, w = t >> 6, l = t & 63, c = l & 15, hi = l >> 4;
    const float* Kbh = Kg + (size_t)bh * Ss * Dd;
    const float* Vbh = Vg + (size_t)bh * Ss * Dd;
    const u16* qh = qlmh + bh * Mm * Dd;
    const u16* ql = qlml + bh * Mm * Dd;
    floatx4 pvC[4];
    float denacc[16];
#pragma unroll
    for (int i = 0; i < 4; i++) pvC[i] = (floatx4){0.f, 0.f, 0.f, 0.f};
#pragma unroll
    for (int i = 0; i < 16; i++) denacc[i] = 0.f;

    for (int tile = 0; tile < 4; ++tile) {
        int s0 = ch * 256 + tile * 64;
        __syncthreads();
        // V loads issued FIRST (named regs)...
        int sl = t >> 2, q = (t & 3) * 16;
        const float4* vp = (const float4*)(Vbh + (size_t)(s0 + sl) * Dd + q);
        float4 v0 = vp[0], v1 = vp[1], v2 = vp[2], v3 = vp[3];
        // ...then K loads (both latencies now overlap in flight)
        int srow = s0 + w * 16 + c;
        const float* kp = Kbh + (size_t)srow * Dd + hi * 8;
        float4 ka = *(const float4*)(kp + 0);
        float4 kb = *(const float4*)(kp + 4);
        float4 kc = *(const float4*)(kp + 32);
        float4 kd = *(const float4*)(kp + 36);
        // V -> tmp: FIFO waitcnt = vmcnt(4), K stays in flight
        {
            float4* dp = (float4*)(tmp + sl * 68 + q);
            dp[0] = v0; dp[1] = v1; dp[2] = v2; dp[3] = v3;
        }
        // split K (waits remaining vmcnt; K arrived under the ds_writes)
        short8 kbh[2], kbl[2];
        {
            float kv[8];
            kv[0] = ka.x; kv[1] = ka.y; kv[2] = ka.z; kv[3] = ka.w;
            kv[4] = kb.x; kv[5] = kb.y; kv[6] = kb.z; kv[7] = kb.w;
            split8(kv, kbh[0], kbl[0]);
            kv[0] = kc.x; kv[1] = kc.y; kv[2] = kc.z; kv[3] = kc.w;
            kv[4] = kd.x; kv[5] = kd.y; kv[6] = kd.z; kv[7] = kd.w;
            split8(kv, kbh[1], kbl[1]);
        }
        {
            floatx4 qkC[4];
#pragma unroll
            for (int i = 0; i < 4; i++) qkC[i] = (floatx4){0.f, 0.f, 0.f, 0.f};
#pragma unroll
            for (int mt = 0; mt < 4; mt++) {
#pragma unroll
                for (int ks = 0; ks < 2; ks++) {
                    short8 aH = *(const short8*)&qh[(mt * 16 + c) * 64 + ks * 32 + hi * 8];
                    short8 aL = *(const short8*)&ql[(mt * 16 + c) * 64 + ks * 32 + hi * 8];
                    qkC[mt] = MFMA(aH, kbh[ks], qkC[mt]);
                    qkC[mt] = MFMA(aL, kbh[ks], qkC[mt]);
                    qkC[mt] = MFMA(aH, kbl[ks], qkC[mt]);
                }
            }
#pragma unroll
            for (int mt = 0; mt < 4; mt++) {
#pragma unroll
                for (int r = 0; r < 4; r++) {
                    float pv = __expf(qkC[mt][r] * SCALE);
                    denacc[mt * 4 + r] += pv;
                    int m = mt * 16 + hi * 4 + r;
                    u16 h, lo; split1(pv, h, lo);
                    Pb[0][swz(m, w * 16 + c)] = h;
                    Pb[1][swz(m, w * 16 + c)] = lo;
                }
            }
        }
        __syncthreads();
        {
            int d = t >> 2, sg = t & 3;
            float v[16];
#pragma unroll
            for (int j = 0; j < 16; j++) v[j] = tmp[(sg * 16 + j) * 68 + d];
            short8 h0, l0, h1, l1;
            split8(v, h0, l0); split8(v + 8, h1, l1);
            *(short8*)&vt[0][swz(d, sg * 16)] = h0;
            *(short8*)&vt[0][swz(d, sg * 16 + 8)] = h1;
            *(short8*)&vt[1][swz(d, sg * 16)] = l0;
            *(short8*)&vt[1][swz(d, sg * 16 + 8)] = l1;
        }
        __syncthreads();
#pragma unroll
        for (int ks = 0; ks < 2; ks++) {
            short8 pah = *(const short8*)&Pb[0][swz(w * 16 + c, ks * 32 + hi * 8)];
            short8 pal = *(const short8*)&Pb[1][swz(w * 16 + c, ks * 32 + hi * 8)];
#pragma unroll
            for (int dt = 0; dt < 4; dt++) {
                short8 vh = *(const short8*)&vt[0][swz(dt * 16 + c, ks * 32 + hi * 8)];
                short8 vl = *(const short8*)&vt[1][swz(dt * 16 + c, ks * 32 + hi * 8)];
                pvC[dt] = MFMA(pah, vh, pvC[dt]);
                pvC[dt] = MFMA(pal, vh, pvC[dt]);
                pvC[dt] = MFMA(pah, vl, pvC[dt]);
            }
        }
    }
    float* nb = pnum + (size_t)(bh * NCH + ch) * 4096;
#pragma unroll
    for (int dt = 0; dt < 4; dt++)
#pragma unroll
        for (int r = 0; r < 4; r++)
            nb[(w * 16 + hi * 4 + r) * 64 + dt * 16 + c] = pvC[dt][r];
#pragma unroll
    for (int i = 0; i < 16; i++) {
        float v = denacc[i];
        v += __shfl_xor(v, 1); v += __shfl_xor(v, 2);
        v += __shfl_xor(v, 4); v += __shfl_xor(v, 8);
        denacc[i] = v;
    }
    if (c == 0) {
        float* db = pden + (size_t)((bh * NCH + ch) * 4 + w) * 64;
#pragma unroll
        for (int mt = 0; mt < 4; mt++)
#pragma unroll
            for (int r = 0; r < 4; r++)
                db[mt * 16 + hi * 4 + r] = denacc[mt * 4 + r];
    }
}

// ---------------- K5: combine partials -> bv, abv = A_tilde @ bv, emit abv^T split bf16 ----------------
__global__ __launch_bounds__(256) void k_bvc(const float* __restrict__ pnum,
                                             const float* __restrict__ pden,
                                             const float* __restrict__ atil,
                                             u16* __restrict__ abvh,
                                             u16* __restrict__ abvl) {
    int bh = blockIdx.x, t = threadIdx.x;
    __shared__ float bvs[Mm][Dd + 1];
    __shared__ float Ams[Mm * (Mm + 1)];
    const float* ab = atil + bh * Mm * Mm;
    for (int i = t; i < Mm * Mm; i += 256) Ams[(i >> 6) * 65 + (i & 63)] = ab[i];
    int m = t >> 2, c = t & 3, d0 = c * 16;
    float den = 0.f;
    const float* db = pden + (size_t)bh * NCH * 4 * 64;
#pragma unroll
    for (int i = 0; i < NCH * 4; i++) den += db[i * 64 + m];
    float acc[16];
#pragma unroll
    for (int i = 0; i < 16; i++) acc[i] = 0.f;
    const float* nb = pnum + (size_t)bh * NCH * 4096;
    for (int ch = 0; ch < NCH; ch++) {
        const float4* pa = (const float4*)(nb + ch * 4096 + m * 64 + d0);
#pragma unroll
        for (int q = 0; q < 4; q++) {
            float4 v = pa[q];
            acc[q * 4 + 0] += v.x; acc[q * 4 + 1] += v.y;
            acc[q * 4 + 2] += v.z; acc[q * 4 + 3] += v.w;
        }
    }
    float inv = 1.0f / den;
#pragma unroll
    for (int ii = 0; ii < 16; ii++) bvs[m][d0 + ii] = acc[ii] * inv;
    __syncthreads();
    int j = t & 63, i0 = (t >> 6) << 4;
    float outv[16];
#pragma unroll
    for (int ii = 0; ii < 16; ii++) outv[ii] = 0.f;
#pragma unroll
    for (int k = 0; k < Mm; k++) {
        float bk = bvs[k][j];
#pragma unroll
        for (int ii = 0; ii < 16; ii++) outv[ii] += Ams[(i0 + ii) * 65 + k] * bk;
    }
    u16* oh = abvh + bh * 4096;
    u16* ol = abvl + bh * 4096;
#pragma unroll
    for (int ii = 0; ii < 16; ii++) {
        u16 h, lo; split1(outv[ii], h, lo);
        oh[j * 64 + i0 + ii] = h;
        ol[j * 64 + i0 + ii] = lo;
    }
}

// ---------------- K6: F_tilde softmax fused with F_tilde @ abv via MFMA ----------------
__global__ __launch_bounds__(256) void k_fout(const float* __restrict__ Qg,
                                              const u16* __restrict__ klmh,
                                              const u16* __restrict__ klml,
                                              const u16* __restrict__ abvh,
                                              const u16* __restrict__ abvl,
                                              float* __restrict__ Og) {
    __shared__ __align__(16) u16 skh[4096], skl[4096], sah[4096], sal[4096];
    __shared__ __align__(16) u16 Pw[4][2][1024];
    int sb = blockIdx.x, bh = blockIdx.y;
    int t = threadIdx.x, w = t >> 6, l = t & 63, c = l & 15, hi = l >> 4;
    {
        const uint4* s1 = (const uint4*)(klmh + bh * 4096);
        const uint4* s2 = (const uint4*)(klml + bh * 4096);
        const uint4* s3 = (const uint4*)(abvh + bh * 4096);
        const uint4* s4 = (const uint4*)(abvl + bh * 4096);
#pragma unroll
        for (int i0 = 0; i0 < 512; i0 += 256) {
            int i = i0 + t;
            int row = i >> 3, chk = i & 7;
            int d = row * 8 + (chk ^ (row & 7));
            ((uint4*)skh)[d] = s1[i];
            ((uint4*)skl)[d] = s2[i];
            ((uint4*)sah)[d] = s3[i];
            ((uint4*)sal)[d] = s4[i];
        }
    }
    const float* qbase = Qg + ((size_t)bh * Ss + (size_t)sb * 256 + w * 16 + c) * Dd + hi * 8;
    float4 qv0[4];
    qv0[0] = *(const float4*)(qbase + 0);
    qv0[1] = *(const float4*)(qbase + 4);
    qv0[2] = *(const float4*)(qbase + 32);
    qv0[3] = *(const float4*)(qbase + 36);
    __syncthreads();
#pragma unroll
    for (int ti = 0; ti < 4; ti++) {
        float4 qn[4];
        if (ti < 3) {
            const float* q2 = qbase + (ti + 1) * 64 * Dd;
            qn[0] = *(const float4*)(q2 + 0);
            qn[1] = *(const float4*)(q2 + 4);
            qn[2] = *(const float4*)(q2 + 32);
            qn[3] = *(const float4*)(q2 + 36);
        }
        short8 qah[2], qal[2];
        {
            float qq[8];
            qq[0] = qv0[0].x; qq[1] = qv0[0].y; qq[2] = qv0[0].z; qq[3] = qv0[0].w;
            qq[4] = qv0[1].x; qq[5] = qv0[1].y; qq[6] = qv0[1].z; qq[7] = qv0[1].w;
            split8(qq, qah[0], qal[0]);
            qq[0] = qv0[2].x; qq[1] = qv0[2].y; qq[2] = qv0[2].z; qq[3] = qv0[2].w;
            qq[4] = qv0[3].x; qq[5] = qv0[3].y; qq[6] = qv0[3].z; qq[7] = qv0[3].w;
            split8(qq, qah[1], qal[1]);
        }
        floatx4 qkC[4];
#pragma unroll
        for (int i = 0; i < 4; i++) qkC[i] = (floatx4){0.f, 0.f, 0.f, 0.f};
        __builtin_amdgcn_s_setprio(1);
#pragma unroll
        for (int mt = 0; mt < 4; mt++) {
#pragma unroll
            for (int ks = 0; ks < 2; ks++) {
                short8 bH = *(const short8*)&skh[swz(mt * 16 + c, ks * 32 + hi * 8)];
                short8 bL = *(const short8*)&skl[swz(mt * 16 + c, ks * 32 + hi * 8)];
                qkC[mt] = MFMA(qah[ks], bH, qkC[mt]);
                qkC[mt] = MFMA(qal[ks], bH, qkC[mt]);
                qkC[mt] = MFMA(qah[ks], bL, qkC[mt]);
            }
        }
        __builtin_amdgcn_s_setprio(0);
        float p[16], dsum[4];
#pragma unroll
        for (int r = 0; r < 4; r++) dsum[r] = 0.f;
#pragma unroll
        for (int mt = 0; mt < 4; mt++)
#pragma unroll
            for (int r = 0; r < 4; r++) {
                float pv = __expf(qkC[mt][r] * SCALE);
                p[mt * 4 + r] = pv;
                dsum[r] += pv;
            }
#pragma unroll
        for (int r = 0; r < 4; r++) {
            float v = dsum[r];
            v += __shfl_xor(v, 1); v += __shfl_xor(v, 2);
            v += __shfl_xor(v, 4); v += __shfl_xor(v, 8);
            dsum[r] = 1.0f / v;
        }
#pragma unroll
        for (int mt = 0; mt < 4; mt++)
#pragma unroll
            for (int r = 0; r < 4; r++) {
                float pv = p[mt * 4 + r] * dsum[r];
                u16 h, lo; split1(pv, h, lo);
                Pw[w][0][swz(hi * 4 + r, mt * 16 + c)] = h;
                Pw[w][1][swz(hi * 4 + r, mt * 16 + c)] = lo;
            }
        asm volatile("s_waitcnt lgkmcnt(0)" ::: "memory");
        __builtin_amdgcn_sched_barrier(0);
        short8 pah[2], pal[2];
#pragma unroll
        for (int ks = 0; ks < 2; ks++) {
            pah[ks] = *(const short8*)&Pw[w][0][swz(c, ks * 32 + hi * 8)];
            pal[ks] = *(const short8*)&Pw[w][1][swz(c, ks * 32 + hi * 8)];
        }
        floatx4 oC[4];
#pragma unroll
        for (int i = 0; i < 4; i++) oC[i] = (floatx4){0.f, 0.f, 0.f, 0.f};
        __builtin_amdgcn_s_setprio(1);
#pragma unroll
        for (int dt = 0; dt < 4; dt++) {
#pragma unroll
            for (int ks = 0; ks < 2; ks++) {
                short8 bH = *(const short8*)&sah[swz(dt * 16 + c, ks * 32 + hi * 8)];
                short8 bL = *(const short8*)&sal[swz(dt * 16 + c, ks * 32 + hi * 8)];
                oC[dt] = MFMA(pah[ks], bH, oC[dt]);
                oC[dt] = MFMA(pal[ks], bH, oC[dt]);
                oC[dt] = MFMA(pah[ks], bL, oC[dt]);
            }
        }
        __builtin_amdgcn_s_setprio(0);
        float* ob = Og + ((size_t)bh * Ss + (size_t)sb * 256 + ti * 64 + w * 16) * Dd;
#pragma unroll
        for (int dt = 0; dt < 4; dt++)
#pragma unroll
            for (int r = 0; r < 4; r++)
                ob[(hi * 4 + r) * 64 + dt * 16 + c] = oC[dt][r];
        qv0[0] = qn[0]; qv0[1] = qn[1]; qv0[2] = qn[2]; qv0[3] = qn[3];
    }
}

extern "C" void kernel_launch(void* const* d_in, const int* in_sizes, int n_in,
                              void* d_out, int out_size, void* d_ws, size_t ws_size,
                              hipStream_t stream) {
    const float* Q = (const float*)d_in[0];
    const float* K = (const float*)d_in[1];
    const float* V = (const float*)d_in[2];
    float* out = (float*)d_out;
    float* ws = (float*)d_ws;
    unsigned int* coef = (unsigned int*)d_ws;
    float* qlm  = ws + 16;
    float* klm  = qlm  + BH * Mm * Dd;
    float* smat = klm  + BH * Mm * Dd;
    float* atil = smat + BH * Mm * Mm;
    float* pnum = atil + BH * Mm * Mm;
    float* pden = pnum + (size_t)BH * NCH * Mm * Dd;
    u16* ub   = (u16*)(pden + (size_t)BH * NCH * 4 * 64);
    u16* qlmh = ub;
    u16* qlml = qlmh + BH * Mm * Dd;
    u16* klmh = qlml + BH * Mm * Dd;
    u16* klml = klmh + BH * Mm * Dd;
    u16* abvh = klml + BH * Mm * Dd;
    u16* abvl = abvh + BH * Mm * Dd;

    hipMemsetAsync(d_ws, 0, 64, stream);

    k_landmarks<<<dim3(8, BH, 2), dim3(256), 0, stream>>>(Q, K, qlm, klm, qlmh, qlml, klmh, klml);
    k_lmsm<<<dim3(BH), dim3(256), 0, stream>>>(qlm, klm, smat, coef);
    k_pinv<<<dim3(BH), dim3(256), 12 * PLN * 2, stream>>>(smat, coef, atil);
    k_bvp<<<dim3(NCH, BH), dim3(256), 0, stream>>>(K, V, qlmh, qlml, pnum, pden);
    k_bvc<<<dim3(BH), dim3(256), 0, stream>>>(pnum, pden, atil, abvh, abvl);
    k_fout<<<dim3(Ss / 256, BH), dim3(256), 0, stream>>>(Q, klmh, klml, abvh, abvl, out);
}

// Round 16
// 146.757 us; speedup vs baseline: 1.1148x; 1.0194x over previous
//
#include <hip/hip_runtime.h>
#include <math.h>

#define BH 48
#define Ss 4096
#define Dd 64
#define Mm 64
#define NCH 16
#define SCALE 0.125f
#define PLN 4096

typedef unsigned int u32;
typedef unsigned short u16;
typedef __attribute__((ext_vector_type(8))) short short8;
typedef __attribute__((ext_vector_type(4))) float floatx4;

union FRAG { uint4 u; short8 s; };

#define MFMA(a,b,c) __builtin_amdgcn_mfma_f32_16x16x32_bf16(a,b,c,0,0,0)

__device__ __forceinline__ u32 pack2_hi(float a, float b) {
    return (__float_as_uint(a) >> 16) | (__float_as_uint(b) & 0xFFFF0000u);
}
__device__ __forceinline__ float trunc_bf(float a) {
    return __uint_as_float(__float_as_uint(a) & 0xFFFF0000u);
}
__device__ __forceinline__ void split1(float v, u16& h, u16& l) {
    u32 u = __float_as_uint(v);
    h = (u16)(u >> 16);
    float r = v - __uint_as_float(u & 0xFFFF0000u);
    l = (u16)(__float_as_uint(r) >> 16);
}
__device__ __forceinline__ void split8(const float* v, short8& h, short8& l) {
    FRAG H, L;
    float r[8];
#pragma unroll
    for (int i = 0; i < 8; i++) r[i] = v[i] - trunc_bf(v[i]);
    H.u.x = pack2_hi(v[0], v[1]); H.u.y = pack2_hi(v[2], v[3]);
    H.u.z = pack2_hi(v[4], v[5]); H.u.w = pack2_hi(v[6], v[7]);
    L.u.x = pack2_hi(r[0], r[1]); L.u.y = pack2_hi(r[2], r[3]);
    L.u.z = pack2_hi(r[4], r[5]); L.u.w = pack2_hi(r[6], r[7]);
    h = H.s; l = L.s;
}
// XOR swizzle for [rows][64] bf16 LDS planes.
__device__ __forceinline__ int swz(int row, int col) {
    return row * 64 + ((((col >> 3) ^ (row & 7)) << 3) | (col & 7));
}

// ---------------- K1: landmarks v2 — 2-half split reduction ----------------
__global__ __launch_bounds__(256) void k_landmarks(const float* __restrict__ Q,
                                                   const float* __restrict__ Kg,
                                                   float* __restrict__ qlm,
                                                   float* __restrict__ klm,
                                                   u16* __restrict__ qlmh, u16* __restrict__ qlml,
                                                   u16* __restrict__ klmh, u16* __restrict__ klml) {
    int g = blockIdx.x, bh = blockIdx.y;
    int t = threadIdx.x;
    int m8 = t >> 5, r5 = t & 31, half = r5 >> 4, d4 = r5 & 15;
    int m = g * 8 + m8;
    __shared__ float4 part[8][16];
    const float* src = blockIdx.z ? Kg : Q;
    float* dst = blockIdx.z ? klm : qlm;
    u16* dh = blockIdx.z ? klmh : qlmh;
    u16* dl = blockIdx.z ? klml : qlml;
    const float* base = src + ((size_t)bh * Ss + (size_t)m * 64 + half * 32) * Dd + d4 * 4;
    float4 acc = make_float4(0.f, 0.f, 0.f, 0.f);
#pragma unroll
    for (int l = 0; l < 32; l++) {
        float4 v = *(const float4*)(base + (size_t)l * Dd);
        acc.x += v.x; acc.y += v.y; acc.z += v.z; acc.w += v.w;
    }
    if (half) part[m8][d4] = acc;
    __syncthreads();
    if (!half) {
        float4 o = part[m8][d4];
        acc.x = (acc.x + o.x) * (1.f / 64.f);
        acc.y = (acc.y + o.y) * (1.f / 64.f);
        acc.z = (acc.z + o.z) * (1.f / 64.f);
        acc.w = (acc.w + o.w) * (1.f / 64.f);
        int idx = (bh * Mm + m) * Dd + d4 * 4;
        *(float4*)(dst + idx) = acc;
        float vv[4] = {acc.x, acc.y, acc.z, acc.w};
        u16 hh[4], ll[4];
#pragma unroll
        for (int i = 0; i < 4; i++) split1(vv[i], hh[i], ll[i]);
        *(uint2*)(dh + idx) = make_uint2((u32)hh[0] | ((u32)hh[1] << 16), (u32)hh[2] | ((u32)hh[3] << 16));
        *(uint2*)(dl + idx) = make_uint2((u32)ll[0] | ((u32)ll[1] << 16), (u32)ll[2] | ((u32)ll[3] << 16));
    }
}

// ---------------- K2: landmark softmax matrix + init_coef (block-reduced atomics) ----------------
__global__ __launch_bounds__(256) void k_lmsm(const float* __restrict__ qlm,
                                              const float* __restrict__ klm,
                                              float* __restrict__ smat,
                                              unsigned int* __restrict__ coef) {
    int bh = blockIdx.x, t = threadIdx.x;
    __shared__ float kl[Mm * Dd];
    __shared__ float ql[Mm * Dd];
    __shared__ float Lp[Mm][Mm + 1];
    const float4* kb = (const float4*)(klm + bh * Mm * Dd);
    const float4* qb = (const float4*)(qlm + bh * Mm * Dd);
    for (int i = t; i < Mm * Dd / 4; i += 256) {
        ((float4*)kl)[i] = kb[i];
        ((float4*)ql)[i] = qb[i];
    }
    __syncthreads();
    int n = t >> 2, c = t & 3;
    float p[16];
#pragma unroll
    for (int jj = 0; jj < 16; jj++) {
        int m = c * 16 + jj;
        float s = 0.f;
#pragma unroll
        for (int d4 = 0; d4 < 16; d4++) {
            int d = (((d4 + c * 4) & 15)) * 4;
            float4 kv = *(const float4*)(kl + m * Dd + d);
            float4 qv = *(const float4*)(ql + n * Dd + d);
            s += qv.x * kv.x + qv.y * kv.y + qv.z * kv.z + qv.w * kv.w;
        }
        p[jj] = s * SCALE;
    }
    float mx = -INFINITY;
#pragma unroll
    for (int jj = 0; jj < 16; jj++) mx = fmaxf(mx, p[jj]);
    mx = fmaxf(mx, __shfl_xor(mx, 1));
    mx = fmaxf(mx, __shfl_xor(mx, 2));
    float den = 0.f;
#pragma unroll
    for (int jj = 0; jj < 16; jj++) { p[jj] = __expf(p[jj] - mx); den += p[jj]; }
    den += __shfl_xor(den, 1);
    den += __shfl_xor(den, 2);
    float inv = 1.0f / den;
#pragma unroll
    for (int jj = 0; jj < 16; jj++) Lp[n][c * 16 + jj] = p[jj] * inv;
    __syncthreads();
    float* sg = smat + bh * Mm * Mm;
    for (int i = t; i < Mm * Mm; i += 256) sg[i] = Lp[i >> 6][i & 63];
    if (t < Mm) {
        float cs = 0.f;
#pragma unroll
        for (int nn = 0; nn < Mm; nn++) cs += Lp[nn][t];
#pragma unroll
        for (int off = 1; off < 64; off <<= 1) cs = fmaxf(cs, __shfl_xor(cs, off));
        if (t == 0) atomicMax(coef + 0, __float_as_uint(cs));
    } else if (t < 2 * Mm) {
        int nn = t - Mm; float rs = 0.f;
#pragma unroll
        for (int m = 0; m < Mm; m++) rs += Lp[nn][m];
#pragma unroll
        for (int off = 1; off < 64; off <<= 1) rs = fmaxf(rs, __shfl_xor(rs, off));
        if (t == Mm) atomicMax(coef + 1, __float_as_uint(rs));
    }
}

// ---------------- K3: Newton-Schulz pinv via split-bf16 MFMA ----------------
__device__ __forceinline__ void pinv_pass(const u16* __restrict__ Ah, const u16* __restrict__ Al,
                                          const u16* __restrict__ Bph, const u16* __restrict__ Bpl,
                                          u16* __restrict__ Oh, u16* __restrict__ Ol,
                                          int w, int c, int hi,
                                          float diag, float sgn, float scl) {
    short8 bfh[2], bfl[2];
#pragma unroll
    for (int ks = 0; ks < 2; ks++) {
        bfh[ks] = *(const short8*)&Bph[swz(w * 16 + c, ks * 32 + hi * 8)];
        bfl[ks] = *(const short8*)&Bpl[swz(w * 16 + c, ks * 32 + hi * 8)];
    }
    int j = w * 16 + c;
#pragma unroll
    for (int ta = 0; ta < 4; ta++) {
        floatx4 acc = (floatx4){0.f, 0.f, 0.f, 0.f};
#pragma unroll
        for (int ks = 0; ks < 2; ks++) {
            short8 afh = *(const short8*)&Ah[swz(ta * 16 + c, ks * 32 + hi * 8)];
            short8 afl = *(const short8*)&Al[swz(ta * 16 + c, ks * 32 + hi * 8)];
            acc = MFMA(afh, bfh[ks], acc);
            acc = MFMA(afl, bfh[ks], acc);
            acc = MFMA(afh, bfl[ks], acc);
        }
        u16 oh[4], ol[4];
#pragma unroll
        for (int r = 0; r < 4; r++) {
            int i = ta * 16 + hi * 4 + r;
            float v = scl * (((i == j) ? diag : 0.f) + sgn * acc[r]);
            split1(v, oh[r], ol[r]);
        }
        int o0 = swz(j, ta * 16 + hi * 4);
        *(u32*)&Oh[o0]     = (u32)oh[0] | ((u32)oh[1] << 16);
        *(u32*)&Oh[o0 + 2] = (u32)oh[2] | ((u32)oh[3] << 16);
        *(u32*)&Ol[o0]     = (u32)ol[0] | ((u32)ol[1] << 16);
        *(u32*)&Ol[o0 + 2] = (u32)ol[2] | ((u32)ol[3] << 16);
    }
}

__global__ __launch_bounds__(256) void k_pinv(const float* __restrict__ smat,
                                              const unsigned int* __restrict__ coef,
                                              float* __restrict__ atil) {
    extern __shared__ u16 P[];
    u16* FaH  = P;             u16* FaL  = P + PLN;
    u16* FxcH = P + 2 * PLN;   u16* FxcL = P + 3 * PLN;
    u16* X0H  = P + 4 * PLN;   u16* X0L  = P + 5 * PLN;
    u16* X1H  = P + 6 * PLN;   u16* X1L  = P + 7 * PLN;
    u16* T1H  = P + 8 * PLN;   u16* T1L  = P + 9 * PLN;
    u16* T2H  = P + 10 * PLN;  u16* T2L  = P + 11 * PLN;
    int bh = blockIdx.x, t = threadIdx.x;
    int w = t >> 6, l = t & 63, c = l & 15, hi = l >> 4;
    float inv = 1.0f / (__uint_as_float(coef[0]) * __uint_as_float(coef[1]));
    {
        int r = t >> 2, kq = (t & 3) * 16;
        const float* ar = smat + bh * 4096 + r * 64 + kq;
        float v[16];
#pragma unroll
        for (int q = 0; q < 4; q++) {
            float4 x = *(const float4*)(ar + q * 4);
            v[q * 4 + 0] = x.x; v[q * 4 + 1] = x.y; v[q * 4 + 2] = x.z; v[q * 4 + 3] = x.w;
        }
        short8 h0, l0, h1, l1;
        split8(v, h0, l0); split8(v + 8, h1, l1);
        *(short8*)&FaH[swz(r, kq)] = h0;     *(short8*)&FaH[swz(r, kq + 8)] = h1;
        *(short8*)&FaL[swz(r, kq)] = l0;     *(short8*)&FaL[swz(r, kq + 8)] = l1;
        float vs[16];
#pragma unroll
        for (int q = 0; q < 16; q++) vs[q] = v[q] * inv;
        split8(vs, h0, l0); split8(vs + 8, h1, l1);
        *(short8*)&FxcH[swz(r, kq)] = h0;    *(short8*)&FxcH[swz(r, kq + 8)] = h1;
        *(short8*)&FxcL[swz(r, kq)] = l0;    *(short8*)&FxcL[swz(r, kq + 8)] = l1;
#pragma unroll
        for (int q = 0; q < 16; q++) {
            u16 h, lo; split1(vs[q], h, lo);
            X0H[swz(kq + q, r)] = h;
            X0L[swz(kq + q, r)] = lo;
        }
    }
    __syncthreads();
    u16 *xrH = X0H, *xrL = X0L, *moH = X1H, *moL = X1L;
    for (int it = 0; it < 6; it++) {
        pinv_pass(FxcH, FxcL, FaH, FaL, moH, moL, w, c, hi, 0.f, 1.f, 1.f);
        pinv_pass(FaH, FaL, FxcH, FxcL, T1H, T1L, w, c, hi, 7.f, -1.f, 1.f);
        __syncthreads();
        pinv_pass(moH, moL, T1H, T1L, T2H, T2L, w, c, hi, 15.f, -1.f, 1.f);
        __syncthreads();
        pinv_pass(moH, moL, T2H, T2L, T1H, T1L, w, c, hi, 13.f, -1.f, 1.f);
        __syncthreads();
        pinv_pass(T1H, T1L, xrH, xrL, moH, moL, w, c, hi, 0.f, 1.f, 0.25f);
        pinv_pass(xrH, xrL, T1H, T1L, FxcH, FxcL, w, c, hi, 0.f, 1.f, 0.25f);
        __syncthreads();
        u16* th = xrH; xrH = moH; moH = th;
        u16* tl = xrL; xrL = moL; moL = tl;
    }
    {
        int i = t >> 2, j0 = (t & 3) * 16;
        FRAG h0, l0, h1, l1;
        h0.s = *(const short8*)&xrH[swz(i, j0)];
        l0.s = *(const short8*)&xrL[swz(i, j0)];
        h1.s = *(const short8*)&xrH[swz(i, j0 + 8)];
        l1.s = *(const short8*)&xrL[swz(i, j0 + 8)];
        float* ob = atil + bh * 4096 + i * 64 + j0;
#pragma unroll
        for (int q = 0; q < 8; q++) {
            ob[q]     = __uint_as_float(((u32)(u16)h0.s[q]) << 16) + __uint_as_float(((u32)(u16)l0.s[q]) << 16);
            ob[q + 8] = __uint_as_float(((u32)(u16)h1.s[q]) << 16) + __uint_as_float(((u32)(u16)l1.s[q]) << 16);
        }
    }
}

// ---------------- K4: B_tilde @ V partials via MFMA (r8 skeleton; tile-invariant
// qlm A-operand fragments hoisted into registers — were re-loaded from global
// inside the tile loop on the MFMA critical path; +64 VGPR is free since LDS
// already caps occupancy at 3 waves/SIMD) ----------------
__global__ __launch_bounds__(256) void k_bvp(const float* __restrict__ Kg,
                                             const float* __restrict__ Vg,
                                             const u16* __restrict__ qlmh,
                                             const u16* __restrict__ qlml,
                                             float* __restrict__ pnum,
                                             float* __restrict__ pden) {
    __shared__ __align__(16) u16 Pb[2][4096];
    __shared__ __align__(16) u16 vt[2][4096];
    __shared__ __align__(16) float tmp[64 * 68];
    int ch = blockIdx.x, bh = blockIdx.y;
    int t = threadIdx.x, w = t >> 6, l = t & 63, c = l & 15, hi = l >> 4;
    const float* Kbh = Kg + (size_t)bh * Ss * Dd;
    const float* Vbh = Vg + (size_t)bh * Ss * Dd;
    const u16* qh = qlmh + bh * Mm * Dd;
    const u16* ql = qlml + bh * Mm * Dd;
    // hoist tile-invariant qlm fragments into registers (static indices only)
    short8 qaH[4][2], qaL[4][2];
#pragma unroll
    for (int mt = 0; mt < 4; mt++)
#pragma unroll
        for (int ks = 0; ks < 2; ks++) {
            qaH[mt][ks] = *(const short8*)&qh[(mt * 16 + c) * 64 + ks * 32 + hi * 8];
            qaL[mt][ks] = *(const short8*)&ql[(mt * 16 + c) * 64 + ks * 32 + hi * 8];
        }
    floatx4 pvC[4];
    float denacc[16];
#pragma unroll
    for (int i = 0; i < 4; i++) pvC[i] = (floatx4){0.f, 0.f, 0.f, 0.f};
#pragma unroll
    for (int i = 0; i < 16; i++) denacc[i] = 0.f;

    for (int tile = 0; tile < 4; ++tile) {
        int s0 = ch * 256 + tile * 64;
        __syncthreads();
        {
            int sl = t >> 2, q = (t & 3) * 16;
            const float4* vp = (const float4*)(Vbh + (size_t)(s0 + sl) * Dd + q);
            float4* dp = (float4*)(tmp + sl * 68 + q);
#pragma unroll
            for (int qq = 0; qq < 4; qq++) dp[qq] = vp[qq];
        }
        {
            int srow = s0 + w * 16 + c;
            const float* kp = Kbh + (size_t)srow * Dd + hi * 8;
            short8 kbh[2], kbl[2];
#pragma unroll
            for (int ks = 0; ks < 2; ks++) {
                float kv[8];
                float4 a = *(const float4*)(kp + ks * 32);
                float4 b = *(const float4*)(kp + ks * 32 + 4);
                kv[0] = a.x; kv[1] = a.y; kv[2] = a.z; kv[3] = a.w;
                kv[4] = b.x; kv[5] = b.y; kv[6] = b.z; kv[7] = b.w;
                split8(kv, kbh[ks], kbl[ks]);
            }
            floatx4 qkC[4];
#pragma unroll
            for (int i = 0; i < 4; i++) qkC[i] = (floatx4){0.f, 0.f, 0.f, 0.f};
#pragma unroll
            for (int mt = 0; mt < 4; mt++) {
#pragma unroll
                for (int ks = 0; ks < 2; ks++) {
                    qkC[mt] = MFMA(qaH[mt][ks], kbh[ks], qkC[mt]);
                    qkC[mt] = MFMA(qaL[mt][ks], kbh[ks], qkC[mt]);
                    qkC[mt] = MFMA(qaH[mt][ks], kbl[ks], qkC[mt]);
                }
            }
#pragma unroll
            for (int mt = 0; mt < 4; mt++) {
#pragma unroll
                for (int r = 0; r < 4; r++) {
                    float pv = __expf(qkC[mt][r] * SCALE);
                    denacc[mt * 4 + r] += pv;
                    int m = mt * 16 + hi * 4 + r;
                    u16 h, lo; split1(pv, h, lo);
                    Pb[0][swz(m, w * 16 + c)] = h;
                    Pb[1][swz(m, w * 16 + c)] = lo;
                }
            }
        }
        __syncthreads();
        {
            int d = t >> 2, sg = t & 3;
            float v[16];
#pragma unroll
            for (int j = 0; j < 16; j++) v[j] = tmp[(sg * 16 + j) * 68 + d];
            short8 h0, l0, h1, l1;
            split8(v, h0, l0); split8(v + 8, h1, l1);
            *(short8*)&vt[0][swz(d, sg * 16)] = h0;
            *(short8*)&vt[0][swz(d, sg * 16 + 8)] = h1;
            *(short8*)&vt[1][swz(d, sg * 16)] = l0;
            *(short8*)&vt[1][swz(d, sg * 16 + 8)] = l1;
        }
        __syncthreads();
#pragma unroll
        for (int ks = 0; ks < 2; ks++) {
            short8 pah = *(const short8*)&Pb[0][swz(w * 16 + c, ks * 32 + hi * 8)];
            short8 pal = *(const short8*)&Pb[1][swz(w * 16 + c, ks * 32 + hi * 8)];
#pragma unroll
            for (int dt = 0; dt < 4; dt++) {
                short8 vh = *(const short8*)&vt[0][swz(dt * 16 + c, ks * 32 + hi * 8)];
                short8 vl = *(const short8*)&vt[1][swz(dt * 16 + c, ks * 32 + hi * 8)];
                pvC[dt] = MFMA(pah, vh, pvC[dt]);
                pvC[dt] = MFMA(pal, vh, pvC[dt]);
                pvC[dt] = MFMA(pah, vl, pvC[dt]);
            }
        }
    }
    float* nb = pnum + (size_t)(bh * NCH + ch) * 4096;
#pragma unroll
    for (int dt = 0; dt < 4; dt++)
#pragma unroll
        for (int r = 0; r < 4; r++)
            nb[(w * 16 + hi * 4 + r) * 64 + dt * 16 + c] = pvC[dt][r];
#pragma unroll
    for (int i = 0; i < 16; i++) {
        float v = denacc[i];
        v += __shfl_xor(v, 1); v += __shfl_xor(v, 2);
        v += __shfl_xor(v, 4); v += __shfl_xor(v, 8);
        denacc[i] = v;
    }
    if (c == 0) {
        float* db = pden + (size_t)((bh * NCH + ch) * 4 + w) * 64;
#pragma unroll
        for (int mt = 0; mt < 4; mt++)
#pragma unroll
            for (int r = 0; r < 4; r++)
                db[mt * 16 + hi * 4 + r] = denacc[mt * 4 + r];
    }
}

// ---------------- K5: combine partials -> bv, abv = A_tilde @ bv, emit abv^T split bf16 ----------------
__global__ __launch_bounds__(256) void k_bvc(const float* __restrict__ pnum,
                                             const float* __restrict__ pden,
                                             const float* __restrict__ atil,
                                             u16* __restrict__ abvh,
                                             u16* __restrict__ abvl) {
    int bh = blockIdx.x, t = threadIdx.x;
    __shared__ float bvs[Mm][Dd + 1];
    __shared__ float Ams[Mm * (Mm + 1)];
    const float* ab = atil + bh * Mm * Mm;
    for (int i = t; i < Mm * Mm; i += 256) Ams[(i >> 6) * 65 + (i & 63)] = ab[i];
    int m = t >> 2, c = t & 3, d0 = c * 16;
    float den = 0.f;
    const float* db = pden + (size_t)bh * NCH * 4 * 64;
#pragma unroll
    for (int i = 0; i < NCH * 4; i++) den += db[i * 64 + m];
    float acc[16];
#pragma unroll
    for (int i = 0; i < 16; i++) acc[i] = 0.f;
    const float* nb = pnum + (size_t)bh * NCH * 4096;
    for (int ch = 0; ch < NCH; ch++) {
        const float4* pa = (const float4*)(nb + ch * 4096 + m * 64 + d0);
#pragma unroll
        for (int q = 0; q < 4; q++) {
            float4 v = pa[q];
            acc[q * 4 + 0] += v.x; acc[q * 4 + 1] += v.y;
            acc[q * 4 + 2] += v.z; acc[q * 4 + 3] += v.w;
        }
    }
    float inv = 1.0f / den;
#pragma unroll
    for (int ii = 0; ii < 16; ii++) bvs[m][d0 + ii] = acc[ii] * inv;
    __syncthreads();
    int j = t & 63, i0 = (t >> 6) << 4;
    float outv[16];
#pragma unroll
    for (int ii = 0; ii < 16; ii++) outv[ii] = 0.f;
#pragma unroll
    for (int k = 0; k < Mm; k++) {
        float bk = bvs[k][j];
#pragma unroll
        for (int ii = 0; ii < 16; ii++) outv[ii] += Ams[(i0 + ii) * 65 + k] * bk;
    }
    u16* oh = abvh + bh * 4096;
    u16* ol = abvl + bh * 4096;
#pragma unroll
    for (int ii = 0; ii < 16; ii++) {
        u16 h, lo; split1(outv[ii], h, lo);
        oh[j * 64 + i0 + ii] = h;
        ol[j * 64 + i0 + ii] = lo;
    }
}

// ---------------- K6: F_tilde softmax fused with F_tilde @ abv via MFMA ----------------
__global__ __launch_bounds__(256) void k_fout(const float* __restrict__ Qg,
                                              const u16* __restrict__ klmh,
                                              const u16* __restrict__ klml,
                                              const u16* __restrict__ abvh,
                                              const u16* __restrict__ abvl,
                                              float* __restrict__ Og) {
    __shared__ __align__(16) u16 skh[4096], skl[4096], sah[4096], sal[4096];
    __shared__ __align__(16) u16 Pw[4][2][1024];
    int sb = blockIdx.x, bh = blockIdx.y;
    int t = threadIdx.x, w = t >> 6, l = t & 63, c = l & 15, hi = l >> 4;
    {
        const uint4* s1 = (const uint4*)(klmh + bh * 4096);
        const uint4* s2 = (const uint4*)(klml + bh * 4096);
        const uint4* s3 = (const uint4*)(abvh + bh * 4096);
        const uint4* s4 = (const uint4*)(abvl + bh * 4096);
#pragma unroll
        for (int i0 = 0; i0 < 512; i0 += 256) {
            int i = i0 + t;
            int row = i >> 3, chk = i & 7;
            int d = row * 8 + (chk ^ (row & 7));
            ((uint4*)skh)[d] = s1[i];
            ((uint4*)skl)[d] = s2[i];
            ((uint4*)sah)[d] = s3[i];
            ((uint4*)sal)[d] = s4[i];
        }
    }
    const float* qbase = Qg + ((size_t)bh * Ss + (size_t)sb * 256 + w * 16 + c) * Dd + hi * 8;
    float4 qv0[4];
    qv0[0] = *(const float4*)(qbase + 0);
    qv0[1] = *(const float4*)(qbase + 4);
    qv0[2] = *(const float4*)(qbase + 32);
    qv0[3] = *(const float4*)(qbase + 36);
    __syncthreads();
#pragma unroll
    for (int ti = 0; ti < 4; ti++) {
        float4 qn[4];
        if (ti < 3) {
            const float* q2 = qbase + (ti + 1) * 64 * Dd;
            qn[0] = *(const float4*)(q2 + 0);
            qn[1] = *(const float4*)(q2 + 4);
            qn[2] = *(const float4*)(q2 + 32);
            qn[3] = *(const float4*)(q2 + 36);
        }
        short8 qah[2], qal[2];
        {
            float qq[8];
            qq[0] = qv0[0].x; qq[1] = qv0[0].y; qq[2] = qv0[0].z; qq[3] = qv0[0].w;
            qq[4] = qv0[1].x; qq[5] = qv0[1].y; qq[6] = qv0[1].z; qq[7] = qv0[1].w;
            split8(qq, qah[0], qal[0]);
            qq[0] = qv0[2].x; qq[1] = qv0[2].y; qq[2] = qv0[2].z; qq[3] = qv0[2].w;
            qq[4] = qv0[3].x; qq[5] = qv0[3].y; qq[6] = qv0[3].z; qq[7] = qv0[3].w;
            split8(qq, qah[1], qal[1]);
        }
        floatx4 qkC[4];
#pragma unroll
        for (int i = 0; i < 4; i++) qkC[i] = (floatx4){0.f, 0.f, 0.f, 0.f};
        __builtin_amdgcn_s_setprio(1);
#pragma unroll
        for (int mt = 0; mt < 4; mt++) {
#pragma unroll
            for (int ks = 0; ks < 2; ks++) {
                short8 bH = *(const short8*)&skh[swz(mt * 16 + c, ks * 32 + hi * 8)];
                short8 bL = *(const short8*)&skl[swz(mt * 16 + c, ks * 32 + hi * 8)];
                qkC[mt] = MFMA(qah[ks], bH, qkC[mt]);
                qkC[mt] = MFMA(qal[ks], bH, qkC[mt]);
                qkC[mt] = MFMA(qah[ks], bL, qkC[mt]);
            }
        }
        __builtin_amdgcn_s_setprio(0);
        float p[16], dsum[4];
#pragma unroll
        for (int r = 0; r < 4; r++) dsum[r] = 0.f;
#pragma unroll
        for (int mt = 0; mt < 4; mt++)
#pragma unroll
            for (int r = 0; r < 4; r++) {
                float pv = __expf(qkC[mt][r] * SCALE);
                p[mt * 4 + r] = pv;
                dsum[r] += pv;
            }
#pragma unroll
        for (int r = 0; r < 4; r++) {
            float v = dsum[r];
            v += __shfl_xor(v, 1); v += __shfl_xor(v, 2);
            v += __shfl_xor(v, 4); v += __shfl_xor(v, 8);
            dsum[r] = 1.0f / v;
        }
#pragma unroll
        for (int mt = 0; mt < 4; mt++)
#pragma unroll
            for (int r = 0; r < 4; r++) {
                float pv = p[mt * 4 + r] * dsum[r];
                u16 h, lo; split1(pv, h, lo);
                Pw[w][0][swz(hi * 4 + r, mt * 16 + c)] = h;
                Pw[w][1][swz(hi * 4 + r, mt * 16 + c)] = lo;
            }
        asm volatile("s_waitcnt lgkmcnt(0)" ::: "memory");
        __builtin_amdgcn_sched_barrier(0);
        short8 pah[2], pal[2];
#pragma unroll
        for (int ks = 0; ks < 2; ks++) {
            pah[ks] = *(const short8*)&Pw[w][0][swz(c, ks * 32 + hi * 8)];
            pal[ks] = *(const short8*)&Pw[w][1][swz(c, ks * 32 + hi * 8)];
        }
        floatx4 oC[4];
#pragma unroll
        for (int i = 0; i < 4; i++) oC[i] = (floatx4){0.f, 0.f, 0.f, 0.f};
        __builtin_amdgcn_s_setprio(1);
#pragma unroll
        for (int dt = 0; dt < 4; dt++) {
#pragma unroll
            for (int ks = 0; ks < 2; ks++) {
                short8 bH = *(const short8*)&sah[swz(dt * 16 + c, ks * 32 + hi * 8)];
                short8 bL = *(const short8*)&sal[swz(dt * 16 + c, ks * 32 + hi * 8)];
                oC[dt] = MFMA(pah[ks], bH, oC[dt]);
                oC[dt] = MFMA(pal[ks], bH, oC[dt]);
                oC[dt] = MFMA(pah[ks], bL, oC[dt]);
            }
        }
        __builtin_amdgcn_s_setprio(0);
        float* ob = Og + ((size_t)bh * Ss + (size_t)sb * 256 + ti * 64 + w * 16) * Dd;
#pragma unroll
        for (int dt = 0; dt < 4; dt++)
#pragma unroll
            for (int r = 0; r < 4; r++)
                ob[(hi * 4 + r) * 64 + dt * 16 + c] = oC[dt][r];
        qv0[0] = qn[0]; qv0[1] = qn[1]; qv0[2] = qn[2]; qv0[3] = qn[3];
    }
}

extern "C" void kernel_launch(void* const* d_in, const int* in_sizes, int n_in,
                              void* d_out, int out_size, void* d_ws, size_t ws_size,
                              hipStream_t stream) {
    const float* Q = (const float*)d_in[0];
    const float* K = (const float*)d_in[1];
    const float* V = (const float*)d_in[2];
    float* out = (float*)d_out;
    float* ws = (float*)d_ws;
    unsigned int* coef = (unsigned int*)d_ws;
    float* qlm  = ws + 16;
    float* klm  = qlm  + BH * Mm * Dd;
    float* smat = klm  + BH * Mm * Dd;
    float* atil = smat + BH * Mm * Mm;
    float* pnum = atil + BH * Mm * Mm;
    float* pden = pnum + (size_t)BH * NCH * Mm * Dd;
    u16* ub   = (u16*)(pden + (size_t)BH * NCH * 4 * 64);
    u16* qlmh = ub;
    u16* qlml = qlmh + BH * Mm * Dd;
    u16* klmh = qlml + BH * Mm * Dd;
    u16* klml = klmh + BH * Mm * Dd;
    u16* abvh = klml + BH * Mm * Dd;
    u16* abvl = abvh + BH * Mm * Dd;

    hipMemsetAsync(d_ws, 0, 64, stream);

    k_landmarks<<<dim3(8, BH, 2), dim3(256), 0, stream>>>(Q, K, qlm, klm, qlmh, qlml, klmh, klml);
    k_lmsm<<<dim3(BH), dim3(256), 0, stream>>>(qlm, klm, smat, coef);
    k_pinv<<<dim3(BH), dim3(256), 12 * PLN * 2, stream>>>(smat, coef, atil);
    k_bvp<<<dim3(NCH, BH), dim3(256), 0, stream>>>(K, V, qlmh, qlml, pnum, pden);
    k_bvc<<<dim3(BH), dim3(256), 0, stream>>>(pnum, pden, atil, abvh, abvl);
    k_fout<<<dim3(Ss / 256, BH), dim3(256), 0, stream>>>(Q, klmh, klml, abvh, abvl, out);
}

// Round 17
// 144.610 us; speedup vs baseline: 1.1313x; 1.0148x over previous
//
#include <hip/hip_runtime.h>
#include <math.h>

#define BH 48
#define Ss 4096
#define Dd 64
#define Mm 64
#define NCH 16
#define SCALE 0.125f
#define PLN 4096

typedef unsigned int u32;
typedef unsigned short u16;
typedef __attribute__((ext_vector_type(8))) short short8;
typedef __attribute__((ext_vector_type(4))) float floatx4;

union FRAG { uint4 u; short8 s; };

#define MFMA(a,b,c) __builtin_amdgcn_mfma_f32_16x16x32_bf16(a,b,c,0,0,0)

__device__ __forceinline__ u32 pack2_hi(float a, float b) {
    return (__float_as_uint(a) >> 16) | (__float_as_uint(b) & 0xFFFF0000u);
}
__device__ __forceinline__ float trunc_bf(float a) {
    return __uint_as_float(__float_as_uint(a) & 0xFFFF0000u);
}
__device__ __forceinline__ void split1(float v, u16& h, u16& l) {
    u32 u = __float_as_uint(v);
    h = (u16)(u >> 16);
    float r = v - __uint_as_float(u & 0xFFFF0000u);
    l = (u16)(__float_as_uint(r) >> 16);
}
__device__ __forceinline__ void split8(const float* v, short8& h, short8& l) {
    FRAG H, L;
    float r[8];
#pragma unroll
    for (int i = 0; i < 8; i++) r[i] = v[i] - trunc_bf(v[i]);
    H.u.x = pack2_hi(v[0], v[1]); H.u.y = pack2_hi(v[2], v[3]);
    H.u.z = pack2_hi(v[4], v[5]); H.u.w = pack2_hi(v[6], v[7]);
    L.u.x = pack2_hi(r[0], r[1]); L.u.y = pack2_hi(r[2], r[3]);
    L.u.z = pack2_hi(r[4], r[5]); L.u.w = pack2_hi(r[6], r[7]);
    h = H.s; l = L.s;
}
// XOR swizzle for [rows][64] bf16 LDS planes.
__device__ __forceinline__ int swz(int row, int col) {
    return row * 64 + ((((col >> 3) ^ (row & 7)) << 3) | (col & 7));
}

// ---------------- K1: landmarks v2 — 2-half split reduction ----------------
__global__ __launch_bounds__(256) void k_landmarks(const float* __restrict__ Q,
                                                   const float* __restrict__ Kg,
                                                   float* __restrict__ qlm,
                                                   float* __restrict__ klm,
                                                   u16* __restrict__ qlmh, u16* __restrict__ qlml,
                                                   u16* __restrict__ klmh, u16* __restrict__ klml) {
    int g = blockIdx.x, bh = blockIdx.y;
    int t = threadIdx.x;
    int m8 = t >> 5, r5 = t & 31, half = r5 >> 4, d4 = r5 & 15;
    int m = g * 8 + m8;
    __shared__ float4 part[8][16];
    const float* src = blockIdx.z ? Kg : Q;
    float* dst = blockIdx.z ? klm : qlm;
    u16* dh = blockIdx.z ? klmh : qlmh;
    u16* dl = blockIdx.z ? klml : qlml;
    const float* base = src + ((size_t)bh * Ss + (size_t)m * 64 + half * 32) * Dd + d4 * 4;
    float4 acc = make_float4(0.f, 0.f, 0.f, 0.f);
#pragma unroll
    for (int l = 0; l < 32; l++) {
        float4 v = *(const float4*)(base + (size_t)l * Dd);
        acc.x += v.x; acc.y += v.y; acc.z += v.z; acc.w += v.w;
    }
    if (half) part[m8][d4] = acc;
    __syncthreads();
    if (!half) {
        float4 o = part[m8][d4];
        acc.x = (acc.x + o.x) * (1.f / 64.f);
        acc.y = (acc.y + o.y) * (1.f / 64.f);
        acc.z = (acc.z + o.z) * (1.f / 64.f);
        acc.w = (acc.w + o.w) * (1.f / 64.f);
        int idx = (bh * Mm + m) * Dd + d4 * 4;
        *(float4*)(dst + idx) = acc;
        float vv[4] = {acc.x, acc.y, acc.z, acc.w};
        u16 hh[4], ll[4];
#pragma unroll
        for (int i = 0; i < 4; i++) split1(vv[i], hh[i], ll[i]);
        *(uint2*)(dh + idx) = make_uint2((u32)hh[0] | ((u32)hh[1] << 16), (u32)hh[2] | ((u32)hh[3] << 16));
        *(uint2*)(dl + idx) = make_uint2((u32)ll[0] | ((u32)ll[1] << 16), (u32)ll[2] | ((u32)ll[3] << 16));
    }
}

// ---------------- K2: landmark softmax matrix + init_coef (block-reduced atomics) ----------------
__global__ __launch_bounds__(256) void k_lmsm(const float* __restrict__ qlm,
                                              const float* __restrict__ klm,
                                              float* __restrict__ smat,
                                              unsigned int* __restrict__ coef) {
    int bh = blockIdx.x, t = threadIdx.x;
    __shared__ float kl[Mm * Dd];
    __shared__ float ql[Mm * Dd];
    __shared__ float Lp[Mm][Mm + 1];
    const float4* kb = (const float4*)(klm + bh * Mm * Dd);
    const float4* qb = (const float4*)(qlm + bh * Mm * Dd);
    for (int i = t; i < Mm * Dd / 4; i += 256) {
        ((float4*)kl)[i] = kb[i];
        ((float4*)ql)[i] = qb[i];
    }
    __syncthreads();
    int n = t >> 2, c = t & 3;
    float p[16];
#pragma unroll
    for (int jj = 0; jj < 16; jj++) {
        int m = c * 16 + jj;
        float s = 0.f;
#pragma unroll
        for (int d4 = 0; d4 < 16; d4++) {
            int d = (((d4 + c * 4) & 15)) * 4;
            float4 kv = *(const float4*)(kl + m * Dd + d);
            float4 qv = *(const float4*)(ql + n * Dd + d);
            s += qv.x * kv.x + qv.y * kv.y + qv.z * kv.z + qv.w * kv.w;
        }
        p[jj] = s * SCALE;
    }
    float mx = -INFINITY;
#pragma unroll
    for (int jj = 0; jj < 16; jj++) mx = fmaxf(mx, p[jj]);
    mx = fmaxf(mx, __shfl_xor(mx, 1));
    mx = fmaxf(mx, __shfl_xor(mx, 2));
    float den = 0.f;
#pragma unroll
    for (int jj = 0; jj < 16; jj++) { p[jj] = __expf(p[jj] - mx); den += p[jj]; }
    den += __shfl_xor(den, 1);
    den += __shfl_xor(den, 2);
    float inv = 1.0f / den;
#pragma unroll
    for (int jj = 0; jj < 16; jj++) Lp[n][c * 16 + jj] = p[jj] * inv;
    __syncthreads();
    float* sg = smat + bh * Mm * Mm;
    for (int i = t; i < Mm * Mm; i += 256) sg[i] = Lp[i >> 6][i & 63];
    if (t < Mm) {
        float cs = 0.f;
#pragma unroll
        for (int nn = 0; nn < Mm; nn++) cs += Lp[nn][t];
#pragma unroll
        for (int off = 1; off < 64; off <<= 1) cs = fmaxf(cs, __shfl_xor(cs, off));
        if (t == 0) atomicMax(coef + 0, __float_as_uint(cs));
    } else if (t < 2 * Mm) {
        int nn = t - Mm; float rs = 0.f;
#pragma unroll
        for (int m = 0; m < Mm; m++) rs += Lp[nn][m];
#pragma unroll
        for (int off = 1; off < 64; off <<= 1) rs = fmaxf(rs, __shfl_xor(rs, off));
        if (t == Mm) atomicMax(coef + 1, __float_as_uint(rs));
    }
}

// ---------------- K3: Newton-Schulz pinv via split-bf16 MFMA ----------------
__device__ __forceinline__ void pinv_pass(const u16* __restrict__ Ah, const u16* __restrict__ Al,
                                          const u16* __restrict__ Bph, const u16* __restrict__ Bpl,
                                          u16* __restrict__ Oh, u16* __restrict__ Ol,
                                          int w, int c, int hi,
                                          float diag, float sgn, float scl) {
    short8 bfh[2], bfl[2];
#pragma unroll
    for (int ks = 0; ks < 2; ks++) {
        bfh[ks] = *(const short8*)&Bph[swz(w * 16 + c, ks * 32 + hi * 8)];
        bfl[ks] = *(const short8*)&Bpl[swz(w * 16 + c, ks * 32 + hi * 8)];
    }
    int j = w * 16 + c;
#pragma unroll
    for (int ta = 0; ta < 4; ta++) {
        floatx4 acc = (floatx4){0.f, 0.f, 0.f, 0.f};
#pragma unroll
        for (int ks = 0; ks < 2; ks++) {
            short8 afh = *(const short8*)&Ah[swz(ta * 16 + c, ks * 32 + hi * 8)];
            short8 afl = *(const short8*)&Al[swz(ta * 16 + c, ks * 32 + hi * 8)];
            acc = MFMA(afh, bfh[ks], acc);
            acc = MFMA(afl, bfh[ks], acc);
            acc = MFMA(afh, bfl[ks], acc);
        }
        u16 oh[4], ol[4];
#pragma unroll
        for (int r = 0; r < 4; r++) {
            int i = ta * 16 + hi * 4 + r;
            float v = scl * (((i == j) ? diag : 0.f) + sgn * acc[r]);
            split1(v, oh[r], ol[r]);
        }
        int o0 = swz(j, ta * 16 + hi * 4);
        *(u32*)&Oh[o0]     = (u32)oh[0] | ((u32)oh[1] << 16);
        *(u32*)&Oh[o0 + 2] = (u32)oh[2] | ((u32)oh[3] << 16);
        *(u32*)&Ol[o0]     = (u32)ol[0] | ((u32)ol[1] << 16);
        *(u32*)&Ol[o0 + 2] = (u32)ol[2] | ((u32)ol[3] << 16);
    }
}

__global__ __launch_bounds__(256) void k_pinv(const float* __restrict__ smat,
                                              const unsigned int* __restrict__ coef,
                                              float* __restrict__ atil) {
    extern __shared__ u16 P[];
    u16* FaH  = P;             u16* FaL  = P + PLN;
    u16* FxcH = P + 2 * PLN;   u16* FxcL = P + 3 * PLN;
    u16* X0H  = P + 4 * PLN;   u16* X0L  = P + 5 * PLN;
    u16* X1H  = P + 6 * PLN;   u16* X1L  = P + 7 * PLN;
    u16* T1H  = P + 8 * PLN;   u16* T1L  = P + 9 * PLN;
    u16* T2H  = P + 10 * PLN;  u16* T2L  = P + 11 * PLN;
    int bh = blockIdx.x, t = threadIdx.x;
    int w = t >> 6, l = t & 63, c = l & 15, hi = l >> 4;
    float inv = 1.0f / (__uint_as_float(coef[0]) * __uint_as_float(coef[1]));
    {
        int r = t >> 2, kq = (t & 3) * 16;
        const float* ar = smat + bh * 4096 + r * 64 + kq;
        float v[16];
#pragma unroll
        for (int q = 0; q < 4; q++) {
            float4 x = *(const float4*)(ar + q * 4);
            v[q * 4 + 0] = x.x; v[q * 4 + 1] = x.y; v[q * 4 + 2] = x.z; v[q * 4 + 3] = x.w;
        }
        short8 h0, l0, h1, l1;
        split8(v, h0, l0); split8(v + 8, h1, l1);
        *(short8*)&FaH[swz(r, kq)] = h0;     *(short8*)&FaH[swz(r, kq + 8)] = h1;
        *(short8*)&FaL[swz(r, kq)] = l0;     *(short8*)&FaL[swz(r, kq + 8)] = l1;
        float vs[16];
#pragma unroll
        for (int q = 0; q < 16; q++) vs[q] = v[q] * inv;
        split8(vs, h0, l0); split8(vs + 8, h1, l1);
        *(short8*)&FxcH[swz(r, kq)] = h0;    *(short8*)&FxcH[swz(r, kq + 8)] = h1;
        *(short8*)&FxcL[swz(r, kq)] = l0;    *(short8*)&FxcL[swz(r, kq + 8)] = l1;
#pragma unroll
        for (int q = 0; q < 16; q++) {
            u16 h, lo; split1(vs[q], h, lo);
            X0H[swz(kq + q, r)] = h;
            X0L[swz(kq + q, r)] = lo;
        }
    }
    __syncthreads();
    u16 *xrH = X0H, *xrL = X0L, *moH = X1H, *moL = X1L;
    for (int it = 0; it < 6; it++) {
        pinv_pass(FxcH, FxcL, FaH, FaL, moH, moL, w, c, hi, 0.f, 1.f, 1.f);
        pinv_pass(FaH, FaL, FxcH, FxcL, T1H, T1L, w, c, hi, 7.f, -1.f, 1.f);
        __syncthreads();
        pinv_pass(moH, moL, T1H, T1L, T2H, T2L, w, c, hi, 15.f, -1.f, 1.f);
        __syncthreads();
        pinv_pass(moH, moL, T2H, T2L, T1H, T1L, w, c, hi, 13.f, -1.f, 1.f);
        __syncthreads();
        pinv_pass(T1H, T1L, xrH, xrL, moH, moL, w, c, hi, 0.f, 1.f, 0.25f);
        pinv_pass(xrH, xrL, T1H, T1L, FxcH, FxcL, w, c, hi, 0.f, 1.f, 0.25f);
        __syncthreads();
        u16* th = xrH; xrH = moH; moH = th;
        u16* tl = xrL; xrL = moL; moL = tl;
    }
    {
        int i = t >> 2, j0 = (t & 3) * 16;
        FRAG h0, l0, h1, l1;
        h0.s = *(const short8*)&xrH[swz(i, j0)];
        l0.s = *(const short8*)&xrL[swz(i, j0)];
        h1.s = *(const short8*)&xrH[swz(i, j0 + 8)];
        l1.s = *(const short8*)&xrL[swz(i, j0 + 8)];
        float* ob = atil + bh * 4096 + i * 64 + j0;
#pragma unroll
        for (int q = 0; q < 8; q++) {
            ob[q]     = __uint_as_float(((u32)(u16)h0.s[q]) << 16) + __uint_as_float(((u32)(u16)l0.s[q]) << 16);
            ob[q + 8] = __uint_as_float(((u32)(u16)h1.s[q]) << 16) + __uint_as_float(((u32)(u16)l1.s[q]) << 16);
        }
    }
}

// ---------------- K4: B_tilde @ V partials via MFMA (r16 base; tmp stripe-padded:
// transpose reads were uniform 4-way bank conflicts (4 sg-groups 1088 f32 apart
// = same banks); +8 f32 per 16-row stripe makes banks 4j+8sg+d = 2-way (free)) ----------------
__global__ __launch_bounds__(256) void k_bvp(const float* __restrict__ Kg,
                                             const float* __restrict__ Vg,
                                             const u16* __restrict__ qlmh,
                                             const u16* __restrict__ qlml,
                                             float* __restrict__ pnum,
                                             float* __restrict__ pden) {
    __shared__ __align__(16) u16 Pb[2][4096];
    __shared__ __align__(16) u16 vt[2][4096];
    __shared__ __align__(16) float tmp[4384];   // 64*68 + 4 stripes * 8 pad
    int ch = blockIdx.x, bh = blockIdx.y;
    int t = threadIdx.x, w = t >> 6, l = t & 63, c = l & 15, hi = l >> 4;
    const float* Kbh = Kg + (size_t)bh * Ss * Dd;
    const float* Vbh = Vg + (size_t)bh * Ss * Dd;
    const u16* qh = qlmh + bh * Mm * Dd;
    const u16* ql = qlml + bh * Mm * Dd;
    short8 qaH[4][2], qaL[4][2];
#pragma unroll
    for (int mt = 0; mt < 4; mt++)
#pragma unroll
        for (int ks = 0; ks < 2; ks++) {
            qaH[mt][ks] = *(const short8*)&qh[(mt * 16 + c) * 64 + ks * 32 + hi * 8];
            qaL[mt][ks] = *(const short8*)&ql[(mt * 16 + c) * 64 + ks * 32 + hi * 8];
        }
    floatx4 pvC[4];
    float denacc[16];
#pragma unroll
    for (int i = 0; i < 4; i++) pvC[i] = (floatx4){0.f, 0.f, 0.f, 0.f};
#pragma unroll
    for (int i = 0; i < 16; i++) denacc[i] = 0.f;

    for (int tile = 0; tile < 4; ++tile) {
        int s0 = ch * 256 + tile * 64;
        __syncthreads();
        {
            int sl = t >> 2, q = (t & 3) * 16;
            const float4* vp = (const float4*)(Vbh + (size_t)(s0 + sl) * Dd + q);
            float4* dp = (float4*)(tmp + sl * 68 + (sl >> 4) * 8 + q);
#pragma unroll
            for (int qq = 0; qq < 4; qq++) dp[qq] = vp[qq];
        }
        {
            int srow = s0 + w * 16 + c;
            const float* kp = Kbh + (size_t)srow * Dd + hi * 8;
            short8 kbh[2], kbl[2];
#pragma unroll
            for (int ks = 0; ks < 2; ks++) {
                float kv[8];
                float4 a = *(const float4*)(kp + ks * 32);
                float4 b = *(const float4*)(kp + ks * 32 + 4);
                kv[0] = a.x; kv[1] = a.y; kv[2] = a.z; kv[3] = a.w;
                kv[4] = b.x; kv[5] = b.y; kv[6] = b.z; kv[7] = b.w;
                split8(kv, kbh[ks], kbl[ks]);
            }
            floatx4 qkC[4];
#pragma unroll
            for (int i = 0; i < 4; i++) qkC[i] = (floatx4){0.f, 0.f, 0.f, 0.f};
#pragma unroll
            for (int mt = 0; mt < 4; mt++) {
#pragma unroll
                for (int ks = 0; ks < 2; ks++) {
                    qkC[mt] = MFMA(qaH[mt][ks], kbh[ks], qkC[mt]);
                    qkC[mt] = MFMA(qaL[mt][ks], kbh[ks], qkC[mt]);
                    qkC[mt] = MFMA(qaH[mt][ks], kbl[ks], qkC[mt]);
                }
            }
#pragma unroll
            for (int mt = 0; mt < 4; mt++) {
#pragma unroll
                for (int r = 0; r < 4; r++) {
                    float pv = __expf(qkC[mt][r] * SCALE);
                    denacc[mt * 4 + r] += pv;
                    int m = mt * 16 + hi * 4 + r;
                    u16 h, lo; split1(pv, h, lo);
                    Pb[0][swz(m, w * 16 + c)] = h;
                    Pb[1][swz(m, w * 16 + c)] = lo;
                }
            }
        }
        __syncthreads();
        {
            int d = t >> 2, sg = t & 3;
            float v[16];
#pragma unroll
            for (int j = 0; j < 16; j++) v[j] = tmp[(sg * 16 + j) * 68 + sg * 8 + d];
            short8 h0, l0, h1, l1;
            split8(v, h0, l0); split8(v + 8, h1, l1);
            *(short8*)&vt[0][swz(d, sg * 16)] = h0;
            *(short8*)&vt[0][swz(d, sg * 16 + 8)] = h1;
            *(short8*)&vt[1][swz(d, sg * 16)] = l0;
            *(short8*)&vt[1][swz(d, sg * 16 + 8)] = l1;
        }
        __syncthreads();
#pragma unroll
        for (int ks = 0; ks < 2; ks++) {
            short8 pah = *(const short8*)&Pb[0][swz(w * 16 + c, ks * 32 + hi * 8)];
            short8 pal = *(const short8*)&Pb[1][swz(w * 16 + c, ks * 32 + hi * 8)];
#pragma unroll
            for (int dt = 0; dt < 4; dt++) {
                short8 vh = *(const short8*)&vt[0][swz(dt * 16 + c, ks * 32 + hi * 8)];
                short8 vl = *(const short8*)&vt[1][swz(dt * 16 + c, ks * 32 + hi * 8)];
                pvC[dt] = MFMA(pah, vh, pvC[dt]);
                pvC[dt] = MFMA(pal, vh, pvC[dt]);
                pvC[dt] = MFMA(pah, vl, pvC[dt]);
            }
        }
    }
    float* nb = pnum + (size_t)(bh * NCH + ch) * 4096;
#pragma unroll
    for (int dt = 0; dt < 4; dt++)
#pragma unroll
        for (int r = 0; r < 4; r++)
            nb[(w * 16 + hi * 4 + r) * 64 + dt * 16 + c] = pvC[dt][r];
#pragma unroll
    for (int i = 0; i < 16; i++) {
        float v = denacc[i];
        v += __shfl_xor(v, 1); v += __shfl_xor(v, 2);
        v += __shfl_xor(v, 4); v += __shfl_xor(v, 8);
        denacc[i] = v;
    }
    if (c == 0) {
        float* db = pden + (size_t)((bh * NCH + ch) * 4 + w) * 64;
#pragma unroll
        for (int mt = 0; mt < 4; mt++)
#pragma unroll
            for (int r = 0; r < 4; r++)
                db[mt * 16 + hi * 4 + r] = denacc[mt * 4 + r];
    }
}

// ---------------- K5: combine partials -> bv, abv = A_tilde @ bv, emit abv^T split bf16 ----------------
__global__ __launch_bounds__(256) void k_bvc(const float* __restrict__ pnum,
                                             const float* __restrict__ pden,
                                             const float* __restrict__ atil,
                                             u16* __restrict__ abvh,
                                             u16* __restrict__ abvl) {
    int bh = blockIdx.x, t = threadIdx.x;
    __shared__ float bvs[Mm][Dd + 1];
    __shared__ float Ams[Mm * (Mm + 1)];
    const float* ab = atil + bh * Mm * Mm;
    for (int i = t; i < Mm * Mm; i += 256) Ams[(i >> 6) * 65 + (i & 63)] = ab[i];
    int m = t >> 2, c = t & 3, d0 = c * 16;
    float den = 0.f;
    const float* db = pden + (size_t)bh * NCH * 4 * 64;
#pragma unroll
    for (int i = 0; i < NCH * 4; i++) den += db[i * 64 + m];
    float acc[16];
#pragma unroll
    for (int i = 0; i < 16; i++) acc[i] = 0.f;
    const float* nb = pnum + (size_t)bh * NCH * 4096;
    for (int ch = 0; ch < NCH; ch++) {
        const float4* pa = (const float4*)(nb + ch * 4096 + m * 64 + d0);
#pragma unroll
        for (int q = 0; q < 4; q++) {
            float4 v = pa[q];
            acc[q * 4 + 0] += v.x; acc[q * 4 + 1] += v.y;
            acc[q * 4 + 2] += v.z; acc[q * 4 + 3] += v.w;
        }
    }
    float inv = 1.0f / den;
#pragma unroll
    for (int ii = 0; ii < 16; ii++) bvs[m][d0 + ii] = acc[ii] * inv;
    __syncthreads();
    int j = t & 63, i0 = (t >> 6) << 4;
    float outv[16];
#pragma unroll
    for (int ii = 0; ii < 16; ii++) outv[ii] = 0.f;
#pragma unroll
    for (int k = 0; k < Mm; k++) {
        float bk = bvs[k][j];
#pragma unroll
        for (int ii = 0; ii < 16; ii++) outv[ii] += Ams[(i0 + ii) * 65 + k] * bk;
    }
    u16* oh = abvh + bh * 4096;
    u16* ol = abvl + bh * 4096;
#pragma unroll
    for (int ii = 0; ii < 16; ii++) {
        u16 h, lo; split1(outv[ii], h, lo);
        oh[j * 64 + i0 + ii] = h;
        ol[j * 64 + i0 + ii] = lo;
    }
}

// ---------------- K6: F_tilde softmax fused with F_tilde @ abv via MFMA ----------------
__global__ __launch_bounds__(256) void k_fout(const float* __restrict__ Qg,
                                              const u16* __restrict__ klmh,
                                              const u16* __restrict__ klml,
                                              const u16* __restrict__ abvh,
                                              const u16* __restrict__ abvl,
                                              float* __restrict__ Og) {
    __shared__ __align__(16) u16 skh[4096], skl[4096], sah[4096], sal[4096];
    __shared__ __align__(16) u16 Pw[4][2][1024];
    int sb = blockIdx.x, bh = blockIdx.y;
    int t = threadIdx.x, w = t >> 6, l = t & 63, c = l & 15, hi = l >> 4;
    {
        const uint4* s1 = (const uint4*)(klmh + bh * 4096);
        const uint4* s2 = (const uint4*)(klml + bh * 4096);
        const uint4* s3 = (const uint4*)(abvh + bh * 4096);
        const uint4* s4 = (const uint4*)(abvl + bh * 4096);
#pragma unroll
        for (int i0 = 0; i0 < 512; i0 += 256) {
            int i = i0 + t;
            int row = i >> 3, chk = i & 7;
            int d = row * 8 + (chk ^ (row & 7));
            ((uint4*)skh)[d] = s1[i];
            ((uint4*)skl)[d] = s2[i];
            ((uint4*)sah)[d] = s3[i];
            ((uint4*)sal)[d] = s4[i];
        }
    }
    const float* qbase = Qg + ((size_t)bh * Ss + (size_t)sb * 256 + w * 16 + c) * Dd + hi * 8;
    float4 qv0[4];
    qv0[0] = *(const float4*)(qbase + 0);
    qv0[1] = *(const float4*)(qbase + 4);
    qv0[2] = *(const float4*)(qbase + 32);
    qv0[3] = *(const float4*)(qbase + 36);
    __syncthreads();
#pragma unroll
    for (int ti = 0; ti < 4; ti++) {
        float4 qn[4];
        if (ti < 3) {
            const float* q2 = qbase + (ti + 1) * 64 * Dd;
            qn[0] = *(const float4*)(q2 + 0);
            qn[1] = *(const float4*)(q2 + 4);
            qn[2] = *(const float4*)(q2 + 32);
            qn[3] = *(const float4*)(q2 + 36);
        }
        short8 qah[2], qal[2];
        {
            float qq[8];
            qq[0] = qv0[0].x; qq[1] = qv0[0].y; qq[2] = qv0[0].z; qq[3] = qv0[0].w;
            qq[4] = qv0[1].x; qq[5] = qv0[1].y; qq[6] = qv0[1].z; qq[7] = qv0[1].w;
            split8(qq, qah[0], qal[0]);
            qq[0] = qv0[2].x; qq[1] = qv0[2].y; qq[2] = qv0[2].z; qq[3] = qv0[2].w;
            qq[4] = qv0[3].x; qq[5] = qv0[3].y; qq[6] = qv0[3].z; qq[7] = qv0[3].w;
            split8(qq, qah[1], qal[1]);
        }
        floatx4 qkC[4];
#pragma unroll
        for (int i = 0; i < 4; i++) qkC[i] = (floatx4){0.f, 0.f, 0.f, 0.f};
        __builtin_amdgcn_s_setprio(1);
#pragma unroll
        for (int mt = 0; mt < 4; mt++) {
#pragma unroll
            for (int ks = 0; ks < 2; ks++) {
                short8 bH = *(const short8*)&skh[swz(mt * 16 + c, ks * 32 + hi * 8)];
                short8 bL = *(const short8*)&skl[swz(mt * 16 + c, ks * 32 + hi * 8)];
                qkC[mt] = MFMA(qah[ks], bH, qkC[mt]);
                qkC[mt] = MFMA(qal[ks], bH, qkC[mt]);
                qkC[mt] = MFMA(qah[ks], bL, qkC[mt]);
            }
        }
        __builtin_amdgcn_s_setprio(0);
        float p[16], dsum[4];
#pragma unroll
        for (int r = 0; r < 4; r++) dsum[r] = 0.f;
#pragma unroll
        for (int mt = 0; mt < 4; mt++)
#pragma unroll
            for (int r = 0; r < 4; r++) {
                float pv = __expf(qkC[mt][r] * SCALE);
                p[mt * 4 + r] = pv;
                dsum[r] += pv;
            }
#pragma unroll
        for (int r = 0; r < 4; r++) {
            float v = dsum[r];
            v += __shfl_xor(v, 1); v += __shfl_xor(v, 2);
            v += __shfl_xor(v, 4); v += __shfl_xor(v, 8);
            dsum[r] = 1.0f / v;
        }
#pragma unroll
        for (int mt = 0; mt < 4; mt++)
#pragma unroll
            for (int r = 0; r < 4; r++) {
                float pv = p[mt * 4 + r] * dsum[r];
                u16 h, lo; split1(pv, h, lo);
                Pw[w][0][swz(hi * 4 + r, mt * 16 + c)] = h;
                Pw[w][1][swz(hi * 4 + r, mt * 16 + c)] = lo;
            }
        asm volatile("s_waitcnt lgkmcnt(0)" ::: "memory");
        __builtin_amdgcn_sched_barrier(0);
        short8 pah[2], pal[2];
#pragma unroll
        for (int ks = 0; ks < 2; ks++) {
            pah[ks] = *(const short8*)&Pw[w][0][swz(c, ks * 32 + hi * 8)];
            pal[ks] = *(const short8*)&Pw[w][1][swz(c, ks * 32 + hi * 8)];
        }
        floatx4 oC[4];
#pragma unroll
        for (int i = 0; i < 4; i++) oC[i] = (floatx4){0.f, 0.f, 0.f, 0.f};
        __builtin_amdgcn_s_setprio(1);
#pragma unroll
        for (int dt = 0; dt < 4; dt++) {
#pragma unroll
            for (int ks = 0; ks < 2; ks++) {
                short8 bH = *(const short8*)&sah[swz(dt * 16 + c, ks * 32 + hi * 8)];
                short8 bL = *(const short8*)&sal[swz(dt * 16 + c, ks * 32 + hi * 8)];
                oC[dt] = MFMA(pah[ks], bH, oC[dt]);
                oC[dt] = MFMA(pal[ks], bH, oC[dt]);
                oC[dt] = MFMA(pah[ks], bL, oC[dt]);
            }
        }
        __builtin_amdgcn_s_setprio(0);
        float* ob = Og + ((size_t)bh * Ss + (size_t)sb * 256 + ti * 64 + w * 16) * Dd;
#pragma unroll
        for (int dt = 0; dt < 4; dt++)
#pragma unroll
            for (int r = 0; r < 4; r++)
                ob[(hi * 4 + r) * 64 + dt * 16 + c] = oC[dt][r];
        qv0[0] = qn[0]; qv0[1] = qn[1]; qv0[2] = qn[2]; qv0[3] = qn[3];
    }
}

extern "C" void kernel_launch(void* const* d_in, const int* in_sizes, int n_in,
                              void* d_out, int out_size, void* d_ws, size_t ws_size,
                              hipStream_t stream) {
    const float* Q = (const float*)d_in[0];
    const float* K = (const float*)d_in[1];
    const float* V = (const float*)d_in[2];
    float* out = (float*)d_out;
    float* ws = (float*)d_ws;
    unsigned int* coef = (unsigned int*)d_ws;
    float* qlm  = ws + 16;
    float* klm  = qlm  + BH * Mm * Dd;
    float* smat = klm  + BH * Mm * Dd;
    float* atil = smat + BH * Mm * Mm;
    float* pnum = atil + BH * Mm * Mm;
    float* pden = pnum + (size_t)BH * NCH * Mm * Dd;
    u16* ub   = (u16*)(pden + (size_t)BH * NCH * 4 * 64);
    u16* qlmh = ub;
    u16* qlml = qlmh + BH * Mm * Dd;
    u16* klmh = qlml + BH * Mm * Dd;
    u16* klml = klmh + BH * Mm * Dd;
    u16* abvh = klml + BH * Mm * Dd;
    u16* abvl = abvh + BH * Mm * Dd;

    hipMemsetAsync(d_ws, 0, 64, stream);

    k_landmarks<<<dim3(8, BH, 2), dim3(256), 0, stream>>>(Q, K, qlm, klm, qlmh, qlml, klmh, klml);
    k_lmsm<<<dim3(BH), dim3(256), 0, stream>>>(qlm, klm, smat, coef);
    k_pinv<<<dim3(BH), dim3(256), 12 * PLN * 2, stream>>>(smat, coef, atil);
    k_bvp<<<dim3(NCH, BH), dim3(256), 0, stream>>>(K, V, qlmh, qlml, pnum, pden);
    k_bvc<<<dim3(BH), dim3(256), 0, stream>>>(pnum, pden, atil, abvh, abvl);
    k_fout<<<dim3(Ss / 256, BH), dim3(256), 0, stream>>>(Q, klmh, klml, abvh, abvl, out);
}